// Round 9
// baseline (297.570 us; speedup 1.0000x reference)
//
#include <hip/hip_runtime.h>
#include <math.h>

#define Bn 8
#define Sn 2048
#define Dn 256
#define Hn 4
#define DHn 64
#define Mn (Bn*Sn)   // 16384 rows

typedef short bf16x8 __attribute__((ext_vector_type(8)));
typedef float f32x2  __attribute__((ext_vector_type(2)));
typedef float f32x4  __attribute__((ext_vector_type(4)));
typedef float f32x16 __attribute__((ext_vector_type(16)));
typedef int   i32x4  __attribute__((ext_vector_type(4)));
typedef unsigned short u16;
typedef unsigned int   u32;
typedef unsigned long long u64;

#if defined(__has_builtin)
#if __has_builtin(__builtin_amdgcn_global_load_lds)
#define HAVE_GLL 1
#endif
#if __has_builtin(__builtin_amdgcn_permlane32_swap)
#define HAVE_PLS 1
#endif
#endif
#ifndef HAVE_GLL
#define HAVE_GLL 0
#endif
#ifndef HAVE_PLS
#define HAVE_PLS 0
#endif

// ---------------------------------------------------------------------------
// helpers
// ---------------------------------------------------------------------------
__device__ __forceinline__ u16 f2b(float f){
    u32 u = __float_as_uint(f);
    u32 r = (u + 0x7fffu + ((u >> 16) & 1u)) >> 16;
    return (u16)r;
}
__device__ __forceinline__ float b2f(u16 h){ return __uint_as_float(((u32)h) << 16); }
__device__ __forceinline__ u32 cvtpk(float lo, float hi){
    u32 r;
    asm("v_cvt_pk_bf16_f32 %0, %1, %2" : "=v"(r) : "v"(lo), "v"(hi));
    return r;
}

// gelu(x) = x - x / (exp2(K1*x + K2*x^3) + 1)   [tanh form, exp2 domain]
__device__ __forceinline__ float gelu_f(float x){
    const float K1 = 2.3021143113f;      // 2*log2(e)*sqrt(2/pi)
    const float K2 = 0.1029390163f;      // K1 * 0.044715
    float x2 = x * x;
    float arg = fmaf(x2 * x, K2, x * K1);
    float e = exp2f(arg);
    float r = __builtin_amdgcn_rcpf(e + 1.0f);
    return x - x * r;
}

// ---------------------------------------------------------------------------
// prep: input cvt (blocks 0..6143) + weight cvt + bias-combine (last 4 blocks)
// ---------------------------------------------------------------------------
struct WtArgs {
    const float* src[13];
    int kdim[13], ndim[13], dstoff[13], t0[13], rm[13];
};
struct BcArgs {
    const float* W2[4];
    const float* b1[4];
    const float* b2[4];
    int off[4];
    float* fb;
    int bc0;
};

__global__ __launch_bounds__(256) void prep_k(const float* __restrict__ lf, const float* __restrict__ gf,
                                              const float* __restrict__ tf,
                                              u16* __restrict__ o0, u16* __restrict__ o1, u16* __restrict__ o2,
                                              WtArgs a, u16* __restrict__ dst, BcArgs bc)
{
    __shared__ float tile[32][33];
    int bx = blockIdx.x;
    if (bx < 6144){
        int part = bx >> 11, blk = bx & 2047;
        const float* s = (part == 0) ? lf : (part == 1) ? gf : tf;
        u16* d = (part == 0) ? o0 : (part == 1) ? o1 : o2;
        size_t base = ((size_t)blk * 256 + threadIdx.x) * 8;
        float4 v0 = *(const float4*)(s + base);
        float4 v1 = *(const float4*)(s + base + 4);
        i32x4 o;
        o[0] = (int)cvtpk(v0.x, v0.y); o[1] = (int)cvtpk(v0.z, v0.w);
        o[2] = (int)cvtpk(v1.x, v1.y); o[3] = (int)cvtpk(v1.z, v1.w);
        *(i32x4*)(d + base) = o;
        return;
    }
    if (bx >= bc.bc0){
        // bias combine: fb[off] = b1 @ W2 + b2 ; zero vector at fb+1024
        int p = bx - bc.bc0, aa = threadIdx.x;
        const float* W2 = bc.W2[p];
        const float* b1 = bc.b1[p];
        const float* b2 = bc.b2[p];
        float s = b2[aa];
        for (int j = 0; j < 256; ++j) s = fmaf(b1[j], W2[(size_t)j*256 + aa], s);
        bc.fb[bc.off[p] + aa] = s;
        if (p == 0) bc.fb[1024 + aa] = 0.f;
        return;
    }
    int tb = bx - 6144;
    int wi = 0;
    #pragma unroll
    for (int i = 1; i < 13; ++i) if (tb >= a.t0[i]) wi = i;
    int tt = tb - a.t0[wi];
    int N = a.ndim[wi], K = a.kdim[wi];
    int ntn = N >> 5;
    int tn = tt % ntn, tk = tt / ntn;
    int n0 = tn * 32, k0 = tk * 32;
    const float* src = a.src[wi];
    u16* out = dst + a.dstoff[wi];
    int r = threadIdx.x >> 5, c = threadIdx.x & 31;
    if (a.rm[wi]){
        #pragma unroll
        for (int rr = 0; rr < 4; ++rr){
            size_t idx = (size_t)(k0 + r*4 + rr) * N + n0 + c;
            out[idx] = f2b(src[idx]);
        }
        return;
    }
    #pragma unroll
    for (int rr = 0; rr < 4; ++rr)
        tile[r*4+rr][c] = src[(size_t)(k0 + r*4 + rr) * N + n0 + c];
    __syncthreads();
    #pragma unroll
    for (int rr = 0; rr < 4; ++rr)
        out[(size_t)(n0 + r*4 + rr) * K + k0 + c] = f2b(tile[c][r*4+rr]);
}

// ---------------------------------------------------------------------------
// GEMM (grouped): C = act((A @ W + bias) * scale). A bf16 [M,K], Wt bf16 [N,K].
// 64x128 tile, BK=32, 4 waves, 2-phase dbuf LDS, counted vmcnt(3), GLL w16.
// Generalized XCD-chunked swizzle (gx, gy pow2; total%8==0).
// ---------------------------------------------------------------------------
struct Grp {
    const u16* A[6];
    const u16* Wt[6];
    const float* bias[6];
    void* C[6];
    float scale[6];
};

template<int ACT, int OUTF32>
__global__ __launch_bounds__(256, 4) void gemm_k(Grp g, int N, int K)
{
    const u32 gx = gridDim.x, gy = gridDim.y;
    const u32 lgx = (u32)__builtin_ctz(gx);
    const u32 lgy = (u32)__builtin_ctz(gy);
    const u32 total = gx * gy * gridDim.z;
    const u32 lid = (blockIdx.z * gy + blockIdx.y) * gx + blockIdx.x;
    const u32 nl = (lid & 7) * (total >> 3) + (lid >> 3);
    const u32 bz = nl >> (lgx + lgy);
    const u32 by = (nl >> lgx) & (gy - 1);
    const u32 bx = nl & (gx - 1);

    const u16* __restrict__ A   = g.A[bz];
    const u16* __restrict__ Wt  = g.Wt[bz];
    const float* __restrict__ bias = g.bias[bz];
    void* __restrict__ Cv = g.C[bz];
    const float scale = g.scale[bz];

    __shared__ u16 sm[2][6144];           // per buf: A tile [64][32] @0, B tile [128][32] @2048
    const int tid = threadIdx.x;
    const int w = tid >> 6, lane = tid & 63;
    const int l15 = lane & 15, l4 = lane >> 4;
    const int wr = w & 1, wc = w >> 1;
    const int bm = by << 6, bn = bx << 7;
    const int xq = l4 ^ ((lane >> 1) & 3);    // read-side swizzle

    f32x4 acc[4][2];
    #pragma unroll
    for (int nf = 0; nf < 4; ++nf)
        #pragma unroll
        for (int mf = 0; mf < 2; ++mf){
            acc[nf][mf][0]=0.f; acc[nf][mf][1]=0.f; acc[nf][mf][2]=0.f; acc[nf][mf][3]=0.f;
        }

    auto STAGE = [&](int buf, int kt){
        #pragma unroll
        for (int j = 0; j < 3; ++j){
            int ch = w*192 + j*64 + lane;     // chunk 0..767 (16B units)
            int isB = ch >= 256;
            int cc  = isB ? ch - 256 : ch;
            int row = cc >> 2, q = cc & 3;
            int qs  = q ^ ((row >> 1) & 3);   // source pre-swizzle
            const u16* src = isB ? (Wt + (size_t)(bn + row) * K + kt + qs*8)
                                 : (A  + (size_t)(bm + row) * K + kt + qs*8);
#if HAVE_GLL
            u16* lb = &sm[buf][(size_t)(w*192 + j*64) * 8];
            __builtin_amdgcn_global_load_lds((const __attribute__((address_space(1))) void*)src,
                                             (__attribute__((address_space(3))) void*)lb, 16, 0, 0);
#else
            *(i32x4*)&sm[buf][(size_t)ch * 8] = *(const i32x4*)src;
#endif
        }
    };

    STAGE(0, 0);
    const int nk = K >> 5;
    for (int t = 0; t < nk; ++t){
        const int cur = t & 1;
        if (t + 1 < nk){
            STAGE(cur ^ 1, (t + 1) << 5);
#if HAVE_GLL
            asm volatile("s_waitcnt vmcnt(3)" ::: "memory");
#endif
        } else {
#if HAVE_GLL
            asm volatile("s_waitcnt vmcnt(0)" ::: "memory");
#endif
        }
        __builtin_amdgcn_s_barrier();
        asm volatile("" ::: "memory");

        const u16* As = sm[cur];
        const u16* Bs = sm[cur] + 2048;
        bf16x8 wf[4], af[2];
        #pragma unroll
        for (int nf = 0; nf < 4; ++nf)
            wf[nf] = *(const bf16x8*)(Bs + (size_t)(wc*64 + nf*16 + l15) * 32 + xq*8);
        #pragma unroll
        for (int mf = 0; mf < 2; ++mf)
            af[mf] = *(const bf16x8*)(As + (size_t)(wr*32 + mf*16 + l15) * 32 + xq*8);
        __builtin_amdgcn_s_setprio(1);
        #pragma unroll
        for (int nf = 0; nf < 4; ++nf)
            #pragma unroll
            for (int mf = 0; mf < 2; ++mf)
                acc[nf][mf] = __builtin_amdgcn_mfma_f32_16x16x32_bf16(wf[nf], af[mf], acc[nf][mf], 0, 0, 0);
        __builtin_amdgcn_s_setprio(0);

        asm volatile("" ::: "memory");
        __builtin_amdgcn_s_barrier();
    }

    // epilogue: D[n][m]: n = bn + wc*64 + nf*16 + l4*4 + r, m = bm + wr*32 + mf*16 + l15
    #pragma unroll
    for (int nf = 0; nf < 4; ++nf){
        const int n0 = bn + wc*64 + nf*16 + l4*4;
        float4 b4 = *(const float4*)(bias + n0);
        #pragma unroll
        for (int mf = 0; mf < 2; ++mf){
            const int m = bm + wr*32 + mf*16 + l15;
            float r0 = (acc[nf][mf][0] + b4.x) * scale;
            float r1 = (acc[nf][mf][1] + b4.y) * scale;
            float r2 = (acc[nf][mf][2] + b4.z) * scale;
            float r3 = (acc[nf][mf][3] + b4.w) * scale;
            if (ACT){ r0 = gelu_f(r0); r1 = gelu_f(r1); r2 = gelu_f(r2); r3 = gelu_f(r3); }
            if (OUTF32){
                float4 o; o.x = r0; o.y = r1; o.z = r2; o.w = r3;
                *(float4*)((float*)Cv + (size_t)m * N + n0) = o;
            } else {
                u64 p = (u64)cvtpk(r0, r1) | ((u64)cvtpk(r2, r3) << 32);
                *(u64*)((u16*)Cv + (size_t)m * N + n0) = p;
            }
        }
    }
}

// ---------------------------------------------------------------------------
// bf16 MFMA flash attention. K fragments loaded DIRECTLY into registers
// (per-lane contiguous 16B: K[kt+c31][kc*16+h*8]) — K never touches LDS.
// V^T double-buffered in padded LDS (reg-stage + byte-perm transpose, T14),
// ONE barrier per tile (guards only V). Q pre-scaled by log2e/8 in producer
// GEMM; fixed m=0 softmax (exact). XCD-chunked 1D block swizzle.
// ---------------------------------------------------------------------------
template<int FUSE>
__global__ __launch_bounds__(256, 2) void attn_k(const u16* __restrict__ Q, const u16* __restrict__ Kp,
                                                 const u16* __restrict__ Vp, u16* __restrict__ O,
                                                 const u16* __restrict__ ADD)
{
    __shared__ u16 Vt[2][4608];          // [buf][d*72 + k], padded rows

    const int tid = threadIdx.x;
    const int w = tid >> 6, lane = tid & 63;
    const int c31 = lane & 31, h = lane >> 5;

    // ---- XCD-chunked swizzle: 512 blocks -> each XCD owns 4 heads x 16 q-blocks
    const int lid = blockIdx.x;
    const int nl = (lid & 7) * 64 + (lid >> 3);
    const int bh = nl >> 4;                          // b*H + h
    const int qb = (nl & 15) << 7;
    const size_t hb = (size_t)(bh >> 2) * Sn * Dn + (size_t)(bh & 3) * DHn;
    const int qrow = qb + w*32 + c31;

    bf16x8 qf[4];
    #pragma unroll
    for (int kc = 0; kc < 4; ++kc)
        qf[kc] = *(const bf16x8*)(Q + hb + (size_t)qrow * Dn + kc*16 + h*8);

    f32x16 ot0, ot1;
    #pragma unroll
    for (int r = 0; r < 16; ++r){ ot0[r] = 0.f; ot1[r] = 0.f; }
    float ll = 0.f;

    // loop-invariant V^T LDS read offsets (u16 units), [72]-padded rows
    int voff0[4], voff1[4];
    #pragma unroll
    for (int kc = 0; kc < 4; ++kc){
        voff0[kc] = c31*72        + kc*16 + h*8;
        voff1[kc] = (32 + c31)*72 + kc*16 + h*8;
    }

    const int vk0 = (tid & 15) * 4, vd0 = (tid >> 4) * 4; // V^T: 4x4 block/thread
    const u32 SEL_LO = 0x05040100u, SEL_HI = 0x07060302u;

    // K fragments in registers (8 x 16B per lane per tile)
    bf16x8 kr0[4], kr1[4];
    auto LOADK = [&](int kt2){
        const u16* kb  = Kp + hb + (size_t)(kt2 + c31) * Dn + h*8;
        const u16* kb2 = kb + 32 * Dn;
        #pragma unroll
        for (int kc = 0; kc < 4; ++kc){
            kr0[kc] = *(const bf16x8*)(kb  + kc*16);
            kr1[kc] = *(const bf16x8*)(kb2 + kc*16);
        }
    };

    u64 v0, v1, v2, v3;
    auto LOADV = [&](int kt2){
        const u16* vb = Vp + hb + (size_t)(kt2 + vk0) * Dn + vd0;
        v0 = *(const u64*)(vb);
        v1 = *(const u64*)(vb + Dn);
        v2 = *(const u64*)(vb + 2*Dn);
        v3 = *(const u64*)(vb + 3*Dn);
    };
    auto WRITEV = [&](int buf){
        u32 a0 = (u32)v0, a1 = (u32)v1, a2 = (u32)v2, a3 = (u32)v3;
        u32 b0 = (u32)(v0 >> 32), b1 = (u32)(v1 >> 32), b2 = (u32)(v2 >> 32), b3 = (u32)(v3 >> 32);
        u64 wd0 = (u64)__builtin_amdgcn_perm(a1, a0, SEL_LO) | ((u64)__builtin_amdgcn_perm(a3, a2, SEL_LO) << 32);
        u64 wd1 = (u64)__builtin_amdgcn_perm(a1, a0, SEL_HI) | ((u64)__builtin_amdgcn_perm(a3, a2, SEL_HI) << 32);
        u64 wd2 = (u64)__builtin_amdgcn_perm(b1, b0, SEL_LO) | ((u64)__builtin_amdgcn_perm(b3, b2, SEL_LO) << 32);
        u64 wd3 = (u64)__builtin_amdgcn_perm(b1, b0, SEL_HI) | ((u64)__builtin_amdgcn_perm(b3, b2, SEL_HI) << 32);
        *(u64*)&Vt[buf][(size_t)(vd0 + 0)*72 + vk0] = wd0;
        *(u64*)&Vt[buf][(size_t)(vd0 + 1)*72 + vk0] = wd1;
        *(u64*)&Vt[buf][(size_t)(vd0 + 2)*72 + vk0] = wd2;
        *(u64*)&Vt[buf][(size_t)(vd0 + 3)*72 + vk0] = wd3;
    };

    // prologue
    LOADK(0);
    LOADV(0);
    WRITEV(0);
    __syncthreads();

    #pragma unroll 2
    for (int t = 0; t < 32; ++t){
        const int c = t & 1;
        const bool more = (t < 31);
        if (more) LOADV((t + 1) << 6);       // T14: V regs, full tile of cover

        // --- S^T = K @ Q^T  from K registers (per lane: 32 scores for q = c31)
        f32x16 s0, s1;
        #pragma unroll
        for (int r = 0; r < 16; ++r){ s0[r] = 0.f; s1[r] = 0.f; }
        __builtin_amdgcn_s_setprio(1);
        #pragma unroll
        for (int kc = 0; kc < 4; ++kc){
            s0 = __builtin_amdgcn_mfma_f32_32x32x16_bf16(kr0[kc], qf[kc], s0, 0, 0, 0);
            s1 = __builtin_amdgcn_mfma_f32_32x32x16_bf16(kr1[kc], qf[kc], s1, 0, 0, 0);
        }
        __builtin_amdgcn_s_setprio(0);

        if (more) LOADK((t + 1) << 6);       // regs free after QK; covered by exp2+PV

        // --- softmax numerator, fixed m=0: p = exp2(s); packed-pair sums
        f32x2 pp0[8], pp1[8];
        f32x2 rv = {0.f, 0.f};
        #pragma unroll
        for (int r = 0; r < 8; ++r){
            pp0[r][0] = exp2f(s0[2*r]); pp0[r][1] = exp2f(s0[2*r+1]);
            pp1[r][0] = exp2f(s1[2*r]); pp1[r][1] = exp2f(s1[2*r+1]);
            rv += pp0[r];
            rv += pp1[r];
        }
        ll += rv[0] + rv[1];

        // --- pack P^T fragments (cvt_pk + permlane32_swap) and PV MFMA
        __builtin_amdgcn_s_setprio(1);
        #pragma unroll
        for (int kc = 0; kc < 4; ++kc){
            const int iA = 2*kc, iB = 2*kc + 1;
            u32 wA0, wA1, wB0, wB1;
            if (kc < 2){
                wA0 = cvtpk(pp0[iA*2+0][0], pp0[iA*2+0][1]);
                wA1 = cvtpk(pp0[iA*2+1][0], pp0[iA*2+1][1]);
                wB0 = cvtpk(pp0[iB*2+0][0], pp0[iB*2+0][1]);
                wB1 = cvtpk(pp0[iB*2+1][0], pp0[iB*2+1][1]);
            } else {
                wA0 = cvtpk(pp1[(iA-4)*2+0][0], pp1[(iA-4)*2+0][1]);
                wA1 = cvtpk(pp1[(iA-4)*2+1][0], pp1[(iA-4)*2+1][1]);
                wB0 = cvtpk(pp1[(iB-4)*2+0][0], pp1[(iB-4)*2+0][1]);
                wB1 = cvtpk(pp1[(iB-4)*2+1][0], pp1[(iB-4)*2+1][1]);
            }
            i32x4 pw;
#if HAVE_PLS
            {
                auto r02 = __builtin_amdgcn_permlane32_swap((int)wA0, (int)wB0, false, false);
                auto r13 = __builtin_amdgcn_permlane32_swap((int)wA1, (int)wB1, false, false);
                pw[0] = r02[0]; pw[1] = r13[0]; pw[2] = r02[1]; pw[3] = r13[1];
            }
#else
            {
                u32 s0v = h ? wA0 : wB0, s1v = h ? wA1 : wB1;
                u32 g0 = (u32)__shfl_xor((int)s0v, 32);
                u32 g1 = (u32)__shfl_xor((int)s1v, 32);
                pw[0] = (int)(h ? g0 : wA0);
                pw[1] = (int)(h ? g1 : wA1);
                pw[2] = (int)(h ? wB0 : g0);
                pw[3] = (int)(h ? wB1 : g1);
            }
#endif
            bf16x8 pb = *(bf16x8*)&pw;
            bf16x8 va  = *(const bf16x8*)&Vt[c][voff0[kc]];
            bf16x8 vb2 = *(const bf16x8*)&Vt[c][voff1[kc]];
            ot0 = __builtin_amdgcn_mfma_f32_32x32x16_bf16(va,  pb, ot0, 0, 0, 0);
            ot1 = __builtin_amdgcn_mfma_f32_32x32x16_bf16(vb2, pb, ot1, 0, 0, 0);
        }
        __builtin_amdgcn_s_setprio(0);

        if (more) WRITEV(c ^ 1);   // write-late; compiler waits vmcnt on the loads
        __syncthreads();           // one barrier per tile (V only)
    }

    // --- combine lane-halves, normalize, store (optional fused add)
    ll += __shfl_xor(ll, 32);
    float inv = 1.0f / ll;
    #pragma unroll
    for (int rg = 0; rg < 4; ++rg){
        int d0 = 8*rg + 4*h;
        float r0 = ot0[4*rg+0]*inv, r1 = ot0[4*rg+1]*inv, r2 = ot0[4*rg+2]*inv, r3 = ot0[4*rg+3]*inv;
        float x0 = ot1[4*rg+0]*inv, x1 = ot1[4*rg+1]*inv, x2 = ot1[4*rg+2]*inv, x3 = ot1[4*rg+3]*inv;
        if (FUSE){
            u64 ga = *(const u64*)&ADD[hb + (size_t)qrow * Dn + d0];
            u64 gb = *(const u64*)&ADD[hb + (size_t)qrow * Dn + 32 + d0];
            r0 += b2f((u16)ga);         r1 += b2f((u16)(ga >> 16));
            r2 += b2f((u16)(ga >> 32)); r3 += b2f((u16)(ga >> 48));
            x0 += b2f((u16)gb);         x1 += b2f((u16)(gb >> 16));
            x2 += b2f((u16)(gb >> 32)); x3 += b2f((u16)(gb >> 48));
        }
        *(u64*)&O[hb + (size_t)qrow * Dn + d0]      = (u64)cvtpk(r0, r1) | ((u64)cvtpk(r2, r3) << 32);
        *(u64*)&O[hb + (size_t)qrow * Dn + 32 + d0] = (u64)cvtpk(x0, x1) | ((u64)cvtpk(x2, x3) << 32);
    }
}

// ---------------------------------------------------------------------------
// Orchestration.
//   glb_ctx + plb_ctx = glb_probs @ (gv + plb_probs @ pv)       [attn fold]
//   pq = lf@(Wl1@Wpq)+bc, gq = gf@(Wg@Wgq)+bc, gk/gv = lf@(Wl2@Wg{k,v})+bc
//   (tail fold REVERTED: bf16-rounding Wm2@Wml costs ~3e-5 absmax — unsafe)
// ---------------------------------------------------------------------------
extern "C" void kernel_launch(void* const* d_in, const int* in_sizes, int n_in,
                              void* d_out, int out_size, void* d_ws, size_t ws_size,
                              hipStream_t stream)
{
    (void)in_sizes; (void)n_in; (void)out_size; (void)ws_size;

    const float* gf  = (const float*)d_in[0];
    const float* lf  = (const float*)d_in[1];
    const float* tf  = (const float*)d_in[2];
    const float* Wl1 = (const float*)d_in[3];  const float* bl1 = (const float*)d_in[4];
    const float* Wl2 = (const float*)d_in[5];  const float* bl2 = (const float*)d_in[6];
    const float* Wg  = (const float*)d_in[7];  const float* bg  = (const float*)d_in[8];
    const float* Wgq = (const float*)d_in[9];  const float* bgq = (const float*)d_in[10];
    const float* Wgk = (const float*)d_in[11]; const float* bgk = (const float*)d_in[12];
    const float* Wgv = (const float*)d_in[13]; const float* bgv = (const float*)d_in[14];
    const float* Wpq = (const float*)d_in[15]; const float* bpq = (const float*)d_in[16];
    const float* bpk = (const float*)d_in[18];
    const float* bpv = (const float*)d_in[20];
    const float* bd  = (const float*)d_in[22];
    const float* bm1 = (const float*)d_in[24];
    const float* bm2 = (const float*)d_in[26];
    const float* Wml = (const float*)d_in[27]; const float* bml = (const float*)d_in[28];

    const float C1 = 0.18033688011112042f;     // log2(e)/8, folded into pq/gq

    u16* ws = (u16*)d_ws;
    const size_t U = (size_t)Mn * Dn;          // 4,194,304 elems (8 MiB bf16)
    u16* S[9];
    for (int i = 0; i < 9; ++i) S[i] = ws + (size_t)i * U;
    u16* wtb = ws + 9 * U;

    const int sq = 65536;
    u16* Wpqt = wtb + 0*sq;  u16* Wgqt = wtb + 1*sq;  u16* Wgkt = wtb + 2*sq;  u16* Wgvt = wtb + 3*sq;
    u16* Wpkt = wtb + 4*sq;  u16* Wpvt = wtb + 5*sq;  u16* Wdt  = wtb + 6*sq;  u16* Wmlt = wtb + 7*sq;
    u16* Wm1t  = wtb + 524288;             // [1024][256] (transposed)
    u16* Wm2t  = wtb + 786432;             // [256][1024] (transposed)
    u16* Wl1rm = wtb + 1048576;
    u16* Wl2rm = wtb + 1114112;
    u16* Wgrm  = wtb + 1179648;
    u16* Wcpqt = wtb + 1245184;            // combined (W1@W2)^T bf16, 4x
    u16* Wcgqt = wtb + 1310720;
    u16* Wcgkt = wtb + 1376256;
    u16* Wcgvt = wtb + 1441792;
    float* fb  = (float*)(wtb + 1507328);  // biases: 4x256 @0, zero @1024

    // --- prep: input cvt + weight cvt + bias-combine, one launch
    WtArgs wa;
    const float* wsrc[13] = {Wpq, Wgq, Wgk, Wgv, (const float*)d_in[17], (const float*)d_in[19],
                             (const float*)d_in[21], Wml,
                             (const float*)d_in[23], (const float*)d_in[25], Wl1, Wl2, Wg};
    const int wdst[13] = {0, sq, 2*sq, 3*sq, 4*sq, 5*sq, 6*sq, 7*sq, 524288, 786432,
                          1048576, 1114112, 1179648};
    for (int i = 0; i < 13; ++i){
        wa.src[i] = wsrc[i];
        wa.kdim[i] = 256; wa.ndim[i] = 256;
        wa.dstoff[i] = wdst[i];
        wa.rm[i] = (i >= 10);
    }
    wa.ndim[8] = 1024;                 // Wm1 [256][1024] -> T [1024][256]
    wa.kdim[9] = 1024;                 // Wm2 [1024][256] -> T [256][1024]
    int acc_t = 0;
    for (int i = 0; i < 13; ++i){
        wa.t0[i] = acc_t;
        acc_t += (wa.ndim[i] >> 5) * (wa.kdim[i] >> 5);
    }
    BcArgs bc;
    bc.W2[0] = Wpq; bc.W2[1] = Wgq; bc.W2[2] = Wgk; bc.W2[3] = Wgv;
    bc.b1[0] = bl1; bc.b1[1] = bg;  bc.b1[2] = bl2; bc.b1[3] = bl2;
    bc.b2[0] = bpq; bc.b2[1] = bgq; bc.b2[2] = bgk; bc.b2[3] = bgv;
    bc.off[0] = 0; bc.off[1] = 256; bc.off[2] = 512; bc.off[3] = 768;
    bc.fb = fb; bc.bc0 = 6144 + acc_t;
    prep_k<<<dim3(6144 + acc_t + 4), 256, 0, stream>>>(lf, gf, tf, S[0], S[1], S[2], wa, wtb, bc);

    auto GN = [&](const Grp& g, int ng, int M, int N, int K, int act, int of32){
        dim3 gr(N / 128, M / 64, ng);
        if (act)        gemm_k<1,0><<<gr, 256, 0, stream>>>(g, N, K);
        else if (of32)  gemm_k<0,1><<<gr, 256, 0, stream>>>(g, N, K);
        else            gemm_k<0,0><<<gr, 256, 0, stream>>>(g, N, K);
    };
    auto G1 = [&](const u16* A, const u16* Wt_, const float* b, void* C, int M, int N, int K,
                  float sc, int act, int of32){
        Grp g{};
        g.A[0] = A; g.Wt[0] = Wt_; g.bias[0] = b; g.C[0] = C; g.scale[0] = sc;
        GN(g, 1, M, N, K, act, of32);
    };

    // --- mini grouped GEMM: Wc^T = W2^T @ W1^T  (M=256, 32 blocks)
    {
        Grp g{};
        g.A[0] = Wpqt; g.Wt[0] = Wl1rm; g.bias[0] = fb + 1024; g.C[0] = Wcpqt; g.scale[0] = 1.f;
        g.A[1] = Wgqt; g.Wt[1] = Wgrm;  g.bias[1] = fb + 1024; g.C[1] = Wcgqt; g.scale[1] = 1.f;
        g.A[2] = Wgkt; g.Wt[2] = Wl2rm; g.bias[2] = fb + 1024; g.C[2] = Wcgkt; g.scale[2] = 1.f;
        g.A[3] = Wgvt; g.Wt[3] = Wl2rm; g.bias[3] = fb + 1024; g.C[3] = Wcgvt; g.scale[3] = 1.f;
        GN(g, 4, 256, 256, 256, 0, 0);
    }

    // --- all 6 projections in ONE grouped launch (direct from raw inputs)
    {
        Grp g{};
        g.A[0] = S[0]; g.Wt[0] = Wcpqt; g.bias[0] = fb + 0;   g.C[0] = S[3]; g.scale[0] = C1;  // pq~
        g.A[1] = S[1]; g.Wt[1] = Wcgqt; g.bias[1] = fb + 256; g.C[1] = S[6]; g.scale[1] = C1;  // gq~
        g.A[2] = S[0]; g.Wt[2] = Wcgkt; g.bias[2] = fb + 512; g.C[2] = S[7]; g.scale[2] = 1.f; // gk
        g.A[3] = S[0]; g.Wt[3] = Wcgvt; g.bias[3] = fb + 768; g.C[3] = S[8]; g.scale[3] = 1.f; // gv
        g.A[4] = S[2]; g.Wt[4] = Wpkt;  g.bias[4] = bpk;      g.C[4] = S[4]; g.scale[4] = 1.f; // pk
        g.A[5] = S[2]; g.Wt[5] = Wpvt;  g.bias[5] = bpv;      g.C[5] = S[5]; g.scale[5] = 1.f; // pv
        GN(g, 6, Mn, 256, 256, 0, 0);
    }

    // --- attention: vsum = attn(pq,pk,pv) + gv ; ctx = attn(gq,gk,vsum)
    attn_k<1><<<dim3(512), 256, 0, stream>>>(S[3], S[4], S[5], S[0], S[8]);
    attn_k<0><<<dim3(512), 256, 0, stream>>>(S[6], S[7], S[0], S[1], nullptr);

    // --- output projection + MLP (unfused tail: numerics-safe)
    G1(S[1], Wdt,  bd,  S[2],  Mn, 256,  256,  1.f, 0, 0);  // out1
    G1(S[2], Wm1t, bm1, S[3],  Mn, 1024, 256,  1.f, 1, 0);  // hid = gelu(...), spans S3..S6
    G1(S[3], Wm2t, bm2, S[7],  Mn, 256,  1024, 1.f, 0, 0);  // out2
    G1(S[7], Wmlt, bml, d_out, Mn, 256,  256,  1.f, 0, 1);  // final (fp32 out)
}

// Round 10
// 240.442 us; speedup vs baseline: 1.2376x; 1.2376x over previous
//
#include <hip/hip_runtime.h>
#include <math.h>

#define Bn 8
#define Sn 2048
#define Dn 256
#define Hn 4
#define DHn 64
#define Mn (Bn*Sn)   // 16384 rows

typedef short bf16x8 __attribute__((ext_vector_type(8)));
typedef float f32x2  __attribute__((ext_vector_type(2)));
typedef float f32x4  __attribute__((ext_vector_type(4)));
typedef float f32x16 __attribute__((ext_vector_type(16)));
typedef int   i32x4  __attribute__((ext_vector_type(4)));
typedef unsigned short u16;
typedef unsigned int   u32;
typedef unsigned long long u64;

#if defined(__has_builtin)
#if __has_builtin(__builtin_amdgcn_global_load_lds)
#define HAVE_GLL 1
#endif
#if __has_builtin(__builtin_amdgcn_permlane32_swap)
#define HAVE_PLS 1
#endif
#endif
#ifndef HAVE_GLL
#define HAVE_GLL 0
#endif
#ifndef HAVE_PLS
#define HAVE_PLS 0
#endif

// ---------------------------------------------------------------------------
// helpers
// ---------------------------------------------------------------------------
__device__ __forceinline__ u16 f2b(float f){
    u32 u = __float_as_uint(f);
    u32 r = (u + 0x7fffu + ((u >> 16) & 1u)) >> 16;
    return (u16)r;
}
__device__ __forceinline__ float b2f(u16 h){ return __uint_as_float(((u32)h) << 16); }
__device__ __forceinline__ u32 cvtpk(float lo, float hi){
    u32 r;
    asm("v_cvt_pk_bf16_f32 %0, %1, %2" : "=v"(r) : "v"(lo), "v"(hi));
    return r;
}

// gelu(x) = x - x / (exp2(K1*x + K2*x^3) + 1)   [tanh form, exp2 domain]
__device__ __forceinline__ float gelu_f(float x){
    const float K1 = 2.3021143113f;      // 2*log2(e)*sqrt(2/pi)
    const float K2 = 0.1029390163f;      // K1 * 0.044715
    float x2 = x * x;
    float arg = fmaf(x2 * x, K2, x * K1);
    float e = exp2f(arg);
    float r = __builtin_amdgcn_rcpf(e + 1.0f);
    return x - x * r;
}

// ---------------------------------------------------------------------------
// prep: input cvt (blocks 0..6143) + weight cvt + bias-combine (last 4 blocks)
// ---------------------------------------------------------------------------
struct WtArgs {
    const float* src[13];
    int kdim[13], ndim[13], dstoff[13], t0[13], rm[13];
};
struct BcArgs {
    const float* W2[4];
    const float* b1[4];
    const float* b2[4];
    int off[4];
    float* fb;
    int bc0;
};

__global__ __launch_bounds__(256) void prep_k(const float* __restrict__ lf, const float* __restrict__ gf,
                                              const float* __restrict__ tf,
                                              u16* __restrict__ o0, u16* __restrict__ o1, u16* __restrict__ o2,
                                              WtArgs a, u16* __restrict__ dst, BcArgs bc)
{
    __shared__ float tile[32][33];
    int bx = blockIdx.x;
    if (bx < 6144){
        int part = bx >> 11, blk = bx & 2047;
        const float* s = (part == 0) ? lf : (part == 1) ? gf : tf;
        u16* d = (part == 0) ? o0 : (part == 1) ? o1 : o2;
        size_t base = ((size_t)blk * 256 + threadIdx.x) * 8;
        float4 v0 = *(const float4*)(s + base);
        float4 v1 = *(const float4*)(s + base + 4);
        i32x4 o;
        o[0] = (int)cvtpk(v0.x, v0.y); o[1] = (int)cvtpk(v0.z, v0.w);
        o[2] = (int)cvtpk(v1.x, v1.y); o[3] = (int)cvtpk(v1.z, v1.w);
        *(i32x4*)(d + base) = o;
        return;
    }
    if (bx >= bc.bc0){
        int p = bx - bc.bc0, aa = threadIdx.x;
        const float* W2 = bc.W2[p];
        const float* b1 = bc.b1[p];
        const float* b2 = bc.b2[p];
        float s = b2[aa];
        for (int j = 0; j < 256; ++j) s = fmaf(b1[j], W2[(size_t)j*256 + aa], s);
        bc.fb[bc.off[p] + aa] = s;
        if (p == 0) bc.fb[1024 + aa] = 0.f;
        return;
    }
    int tb = bx - 6144;
    int wi = 0;
    #pragma unroll
    for (int i = 1; i < 13; ++i) if (tb >= a.t0[i]) wi = i;
    int tt = tb - a.t0[wi];
    int N = a.ndim[wi], K = a.kdim[wi];
    int ntn = N >> 5;
    int tn = tt % ntn, tk = tt / ntn;
    int n0 = tn * 32, k0 = tk * 32;
    const float* src = a.src[wi];
    u16* out = dst + a.dstoff[wi];
    int r = threadIdx.x >> 5, c = threadIdx.x & 31;
    if (a.rm[wi]){
        #pragma unroll
        for (int rr = 0; rr < 4; ++rr){
            size_t idx = (size_t)(k0 + r*4 + rr) * N + n0 + c;
            out[idx] = f2b(src[idx]);
        }
        return;
    }
    #pragma unroll
    for (int rr = 0; rr < 4; ++rr)
        tile[r*4+rr][c] = src[(size_t)(k0 + r*4 + rr) * N + n0 + c];
    __syncthreads();
    #pragma unroll
    for (int rr = 0; rr < 4; ++rr)
        out[(size_t)(n0 + r*4 + rr) * K + k0 + c] = f2b(tile[c][r*4+rr]);
}

// ---------------------------------------------------------------------------
// GEMM (grouped): C = act((A @ W + bias) * scale). A bf16 [M,K], Wt bf16 [N,K].
// 64x128 tile, BK=32, 4 waves, 2-phase dbuf LDS, counted vmcnt(3), GLL w16.
// Generalized XCD-chunked swizzle (gx, gy pow2; total%8==0).
// ---------------------------------------------------------------------------
struct Grp {
    const u16* A[6];
    const u16* Wt[6];
    const float* bias[6];
    void* C[6];
    float scale[6];
};

template<int ACT, int OUTF32>
__global__ __launch_bounds__(256, 4) void gemm_k(Grp g, int N, int K)
{
    const u32 gx = gridDim.x, gy = gridDim.y;
    const u32 lgx = (u32)__builtin_ctz(gx);
    const u32 lgy = (u32)__builtin_ctz(gy);
    const u32 total = gx * gy * gridDim.z;
    const u32 lid = (blockIdx.z * gy + blockIdx.y) * gx + blockIdx.x;
    const u32 nl = (lid & 7) * (total >> 3) + (lid >> 3);
    const u32 bz = nl >> (lgx + lgy);
    const u32 by = (nl >> lgx) & (gy - 1);
    const u32 bx = nl & (gx - 1);

    const u16* __restrict__ A   = g.A[bz];
    const u16* __restrict__ Wt  = g.Wt[bz];
    const float* __restrict__ bias = g.bias[bz];
    void* __restrict__ Cv = g.C[bz];
    const float scale = g.scale[bz];

    __shared__ u16 sm[2][6144];           // per buf: A tile [64][32] @0, B tile [128][32] @2048
    const int tid = threadIdx.x;
    const int w = tid >> 6, lane = tid & 63;
    const int l15 = lane & 15, l4 = lane >> 4;
    const int wr = w & 1, wc = w >> 1;
    const int bm = by << 6, bn = bx << 7;
    const int xq = l4 ^ ((lane >> 1) & 3);    // read-side swizzle

    f32x4 acc[4][2];
    #pragma unroll
    for (int nf = 0; nf < 4; ++nf)
        #pragma unroll
        for (int mf = 0; mf < 2; ++mf){
            acc[nf][mf][0]=0.f; acc[nf][mf][1]=0.f; acc[nf][mf][2]=0.f; acc[nf][mf][3]=0.f;
        }

    auto STAGE = [&](int buf, int kt){
        #pragma unroll
        for (int j = 0; j < 3; ++j){
            int ch = w*192 + j*64 + lane;     // chunk 0..767 (16B units)
            int isB = ch >= 256;
            int cc  = isB ? ch - 256 : ch;
            int row = cc >> 2, q = cc & 3;
            int qs  = q ^ ((row >> 1) & 3);   // source pre-swizzle
            const u16* src = isB ? (Wt + (size_t)(bn + row) * K + kt + qs*8)
                                 : (A  + (size_t)(bm + row) * K + kt + qs*8);
#if HAVE_GLL
            u16* lb = &sm[buf][(size_t)(w*192 + j*64) * 8];
            __builtin_amdgcn_global_load_lds((const __attribute__((address_space(1))) void*)src,
                                             (__attribute__((address_space(3))) void*)lb, 16, 0, 0);
#else
            *(i32x4*)&sm[buf][(size_t)ch * 8] = *(const i32x4*)src;
#endif
        }
    };

    STAGE(0, 0);
    const int nk = K >> 5;
    for (int t = 0; t < nk; ++t){
        const int cur = t & 1;
        if (t + 1 < nk){
            STAGE(cur ^ 1, (t + 1) << 5);
#if HAVE_GLL
            asm volatile("s_waitcnt vmcnt(3)" ::: "memory");
#endif
        } else {
#if HAVE_GLL
            asm volatile("s_waitcnt vmcnt(0)" ::: "memory");
#endif
        }
        __builtin_amdgcn_s_barrier();
        asm volatile("" ::: "memory");

        const u16* As = sm[cur];
        const u16* Bs = sm[cur] + 2048;
        bf16x8 wf[4], af[2];
        #pragma unroll
        for (int nf = 0; nf < 4; ++nf)
            wf[nf] = *(const bf16x8*)(Bs + (size_t)(wc*64 + nf*16 + l15) * 32 + xq*8);
        #pragma unroll
        for (int mf = 0; mf < 2; ++mf)
            af[mf] = *(const bf16x8*)(As + (size_t)(wr*32 + mf*16 + l15) * 32 + xq*8);
        __builtin_amdgcn_s_setprio(1);
        #pragma unroll
        for (int nf = 0; nf < 4; ++nf)
            #pragma unroll
            for (int mf = 0; mf < 2; ++mf)
                acc[nf][mf] = __builtin_amdgcn_mfma_f32_16x16x32_bf16(wf[nf], af[mf], acc[nf][mf], 0, 0, 0);
        __builtin_amdgcn_s_setprio(0);

        asm volatile("" ::: "memory");
        __builtin_amdgcn_s_barrier();
    }

    // epilogue: D[n][m]: n = bn + wc*64 + nf*16 + l4*4 + r, m = bm + wr*32 + mf*16 + l15
    #pragma unroll
    for (int nf = 0; nf < 4; ++nf){
        const int n0 = bn + wc*64 + nf*16 + l4*4;
        float4 b4 = *(const float4*)(bias + n0);
        #pragma unroll
        for (int mf = 0; mf < 2; ++mf){
            const int m = bm + wr*32 + mf*16 + l15;
            float r0 = (acc[nf][mf][0] + b4.x) * scale;
            float r1 = (acc[nf][mf][1] + b4.y) * scale;
            float r2 = (acc[nf][mf][2] + b4.z) * scale;
            float r3 = (acc[nf][mf][3] + b4.w) * scale;
            if (ACT){ r0 = gelu_f(r0); r1 = gelu_f(r1); r2 = gelu_f(r2); r3 = gelu_f(r3); }
            if (OUTF32){
                float4 o; o.x = r0; o.y = r1; o.z = r2; o.w = r3;
                *(float4*)((float*)Cv + (size_t)m * N + n0) = o;
            } else {
                u64 p = (u64)cvtpk(r0, r1) | ((u64)cvtpk(r2, r3) << 32);
                *(u64*)((u16*)Cv + (size_t)m * N + n0) = p;
            }
        }
    }
}

// ---------------------------------------------------------------------------
// bf16 MFMA flash attention, ROLE-SPLIT staging. 512 threads = 8 waves, each
// wave computes 32 q rows (256 q/block). Waves 0-3 stage V (reg + byte-perm
// transpose), waves 4-7 stage K — per-CU staging volume HALVES vs 4-wave
// blocks (same staged bytes feed 2x compute). K,V double-buffered [64][72]-
// padded LDS, ONE barrier per tile. Q pre-scaled by log2e/8 in producer GEMM;
// fixed m=0 softmax (exact). XCD-chunked swizzle: 256 blocks = 1/CU, 8 waves.
// ---------------------------------------------------------------------------
template<int FUSE>
__global__ __launch_bounds__(512, 2) void attn_k(const u16* __restrict__ Q, const u16* __restrict__ Kp,
                                                 const u16* __restrict__ Vp, u16* __restrict__ O,
                                                 const u16* __restrict__ ADD)
{
    __shared__ u16 Kl[2][4608];          // [buf][64*72], padded rows
    __shared__ u16 Vt[2][4608];          // [buf][d*72 + k], padded rows

    const int tid = threadIdx.x;
    const int w = tid >> 6, lane = tid & 63;
    const int c31 = lane & 31, h = lane >> 5;

    // ---- XCD-chunked swizzle: 256 blocks -> each XCD owns 4 heads x 8 q-blocks
    const int lid = blockIdx.x;
    const int nl = (lid & 7) * 32 + (lid >> 3);
    const int bh = nl >> 3;                          // b*H + h
    const int qb = (nl & 7) << 8;                    // 256 q rows per block
    const size_t hb = (size_t)(bh >> 2) * Sn * Dn + (size_t)(bh & 3) * DHn;
    const int qrow = qb + w*32 + c31;

    bf16x8 qf[4];
    #pragma unroll
    for (int kc = 0; kc < 4; ++kc)
        qf[kc] = *(const bf16x8*)(Q + hb + (size_t)qrow * Dn + kc*16 + h*8);

    f32x16 ot0, ot1;
    #pragma unroll
    for (int r = 0; r < 16; ++r){ ot0[r] = 0.f; ot1[r] = 0.f; }
    float ll = 0.f;

    // loop-invariant LDS read offsets (u16 units), [72]-padded rows
    int koff0[4], koff1[4];
    #pragma unroll
    for (int kc = 0; kc < 4; ++kc){
        koff0[kc] = c31*72        + kc*16 + h*8;
        koff1[kc] = (32 + c31)*72 + kc*16 + h*8;
    }

    // staging roles: waves 4-7 stage K, waves 0-3 stage V (wave-uniform split)
    const int isK = tid >= 256;
    const int t2 = tid & 255;
    const int krow = t2 >> 2, kq = t2 & 3;              // K: 2x16B/thread over 256 thr
    const int vk0 = (t2 & 15) * 4, vd0 = (t2 >> 4) * 4; // V^T: 4x4 block/thread
    const u32 SEL_LO = 0x05040100u, SEL_HI = 0x07060302u;

    i32x4 kr0, kr1;
    u64 v0, v1, v2, v3;
    auto LOADKV = [&](int kt2){
        if (isK){
            const u16* kb = Kp + hb + (size_t)(kt2 + krow) * Dn + kq*8;
            kr0 = *(const i32x4*)kb;
            kr1 = *(const i32x4*)(kb + 32);
        } else {
            const u16* vb = Vp + hb + (size_t)(kt2 + vk0) * Dn + vd0;
            v0 = *(const u64*)(vb);
            v1 = *(const u64*)(vb + Dn);
            v2 = *(const u64*)(vb + 2*Dn);
            v3 = *(const u64*)(vb + 3*Dn);
        }
    };
    auto WRITEKV = [&](int buf){
        if (isK){
            *(i32x4*)&Kl[buf][(size_t)krow*72 + kq*8]      = kr0;
            *(i32x4*)&Kl[buf][(size_t)krow*72 + kq*8 + 32] = kr1;
        } else {
            u32 a0 = (u32)v0, a1 = (u32)v1, a2 = (u32)v2, a3 = (u32)v3;
            u32 b0 = (u32)(v0 >> 32), b1 = (u32)(v1 >> 32), b2 = (u32)(v2 >> 32), b3 = (u32)(v3 >> 32);
            u64 wd0 = (u64)__builtin_amdgcn_perm(a1, a0, SEL_LO) | ((u64)__builtin_amdgcn_perm(a3, a2, SEL_LO) << 32);
            u64 wd1 = (u64)__builtin_amdgcn_perm(a1, a0, SEL_HI) | ((u64)__builtin_amdgcn_perm(a3, a2, SEL_HI) << 32);
            u64 wd2 = (u64)__builtin_amdgcn_perm(b1, b0, SEL_LO) | ((u64)__builtin_amdgcn_perm(b3, b2, SEL_LO) << 32);
            u64 wd3 = (u64)__builtin_amdgcn_perm(b1, b0, SEL_HI) | ((u64)__builtin_amdgcn_perm(b3, b2, SEL_HI) << 32);
            *(u64*)&Vt[buf][(size_t)(vd0 + 0)*72 + vk0] = wd0;
            *(u64*)&Vt[buf][(size_t)(vd0 + 1)*72 + vk0] = wd1;
            *(u64*)&Vt[buf][(size_t)(vd0 + 2)*72 + vk0] = wd2;
            *(u64*)&Vt[buf][(size_t)(vd0 + 3)*72 + vk0] = wd3;
        }
    };

    // prologue
    LOADKV(0);
    WRITEKV(0);
    __syncthreads();

    #pragma unroll 2
    for (int t = 0; t < 32; ++t){
        const int c = t & 1;
        const bool more = (t < 31);
        if (more) LOADKV((t + 1) << 6);      // T14: issue early, full tile of cover

        // --- S^T = K @ Q^T  (per lane: 32 pre-scaled scores for q = c31)
        f32x16 s0, s1;
        #pragma unroll
        for (int r = 0; r < 16; ++r){ s0[r] = 0.f; s1[r] = 0.f; }
        __builtin_amdgcn_s_setprio(1);
        #pragma unroll
        for (int kc = 0; kc < 4; ++kc){
            bf16x8 k0 = *(const bf16x8*)&Kl[c][koff0[kc]];
            bf16x8 k1 = *(const bf16x8*)&Kl[c][koff1[kc]];
            s0 = __builtin_amdgcn_mfma_f32_32x32x16_bf16(k0, qf[kc], s0, 0, 0, 0);
            s1 = __builtin_amdgcn_mfma_f32_32x32x16_bf16(k1, qf[kc], s1, 0, 0, 0);
        }
        __builtin_amdgcn_s_setprio(0);

        // --- softmax numerator, fixed m=0: p = exp2(s); packed-pair sums
        f32x2 pp0[8], pp1[8];
        f32x2 rv = {0.f, 0.f};
        #pragma unroll
        for (int r = 0; r < 8; ++r){
            pp0[r][0] = exp2f(s0[2*r]); pp0[r][1] = exp2f(s0[2*r+1]);
            pp1[r][0] = exp2f(s1[2*r]); pp1[r][1] = exp2f(s1[2*r+1]);
            rv += pp0[r];
            rv += pp1[r];
        }
        ll += rv[0] + rv[1];

        // --- pack P^T fragments (cvt_pk + permlane32_swap) and PV MFMA
        __builtin_amdgcn_s_setprio(1);
        #pragma unroll
        for (int kc = 0; kc < 4; ++kc){
            const int iA = 2*kc, iB = 2*kc + 1;
            u32 wA0, wA1, wB0, wB1;
            if (kc < 2){
                wA0 = cvtpk(pp0[iA*2+0][0], pp0[iA*2+0][1]);
                wA1 = cvtpk(pp0[iA*2+1][0], pp0[iA*2+1][1]);
                wB0 = cvtpk(pp0[iB*2+0][0], pp0[iB*2+0][1]);
                wB1 = cvtpk(pp0[iB*2+1][0], pp0[iB*2+1][1]);
            } else {
                wA0 = cvtpk(pp1[(iA-4)*2+0][0], pp1[(iA-4)*2+0][1]);
                wA1 = cvtpk(pp1[(iA-4)*2+1][0], pp1[(iA-4)*2+1][1]);
                wB0 = cvtpk(pp1[(iB-4)*2+0][0], pp1[(iB-4)*2+0][1]);
                wB1 = cvtpk(pp1[(iB-4)*2+1][0], pp1[(iB-4)*2+1][1]);
            }
            i32x4 pw;
#if HAVE_PLS
            {
                auto r02 = __builtin_amdgcn_permlane32_swap((int)wA0, (int)wB0, false, false);
                auto r13 = __builtin_amdgcn_permlane32_swap((int)wA1, (int)wB1, false, false);
                pw[0] = r02[0]; pw[1] = r13[0]; pw[2] = r02[1]; pw[3] = r13[1];
            }
#else
            {
                u32 s0v = h ? wA0 : wB0, s1v = h ? wA1 : wB1;
                u32 g0 = (u32)__shfl_xor((int)s0v, 32);
                u32 g1 = (u32)__shfl_xor((int)s1v, 32);
                pw[0] = (int)(h ? g0 : wA0);
                pw[1] = (int)(h ? g1 : wA1);
                pw[2] = (int)(h ? wB0 : g0);
                pw[3] = (int)(h ? wB1 : g1);
            }
#endif
            bf16x8 pb = *(bf16x8*)&pw;
            bf16x8 va  = *(const bf16x8*)&Vt[c][koff0[kc]];
            bf16x8 vb2 = *(const bf16x8*)&Vt[c][koff1[kc]];
            ot0 = __builtin_amdgcn_mfma_f32_32x32x16_bf16(va,  pb, ot0, 0, 0, 0);
            ot1 = __builtin_amdgcn_mfma_f32_32x32x16_bf16(vb2, pb, ot1, 0, 0, 0);
        }
        __builtin_amdgcn_s_setprio(0);

        if (more) WRITEKV(c ^ 1);   // write-late; compiler waits vmcnt on the loads
        __syncthreads();            // one barrier per tile
    }

    // --- combine lane-halves, normalize, store (optional fused add)
    ll += __shfl_xor(ll, 32);
    float inv = 1.0f / ll;
    #pragma unroll
    for (int rg = 0; rg < 4; ++rg){
        int d0 = 8*rg + 4*h;
        float r0 = ot0[4*rg+0]*inv, r1 = ot0[4*rg+1]*inv, r2 = ot0[4*rg+2]*inv, r3 = ot0[4*rg+3]*inv;
        float x0 = ot1[4*rg+0]*inv, x1 = ot1[4*rg+1]*inv, x2 = ot1[4*rg+2]*inv, x3 = ot1[4*rg+3]*inv;
        if (FUSE){
            u64 ga = *(const u64*)&ADD[hb + (size_t)qrow * Dn + d0];
            u64 gb = *(const u64*)&ADD[hb + (size_t)qrow * Dn + 32 + d0];
            r0 += b2f((u16)ga);         r1 += b2f((u16)(ga >> 16));
            r2 += b2f((u16)(ga >> 32)); r3 += b2f((u16)(ga >> 48));
            x0 += b2f((u16)gb);         x1 += b2f((u16)(gb >> 16));
            x2 += b2f((u16)(gb >> 32)); x3 += b2f((u16)(gb >> 48));
        }
        *(u64*)&O[hb + (size_t)qrow * Dn + d0]      = (u64)cvtpk(r0, r1) | ((u64)cvtpk(r2, r3) << 32);
        *(u64*)&O[hb + (size_t)qrow * Dn + 32 + d0] = (u64)cvtpk(x0, x1) | ((u64)cvtpk(x2, x3) << 32);
    }
}

// ---------------------------------------------------------------------------
// Orchestration.
//   glb_ctx + plb_ctx = glb_probs @ (gv + plb_probs @ pv)       [attn fold]
//   pq = lf@(Wl1@Wpq)+bc, gq = gf@(Wg@Wgq)+bc, gk/gv = lf@(Wl2@Wg{k,v})+bc
//   (tail fold stays REVERTED: bf16 rounding of Wm2@Wml costs ~3e-5 absmax)
// ---------------------------------------------------------------------------
extern "C" void kernel_launch(void* const* d_in, const int* in_sizes, int n_in,
                              void* d_out, int out_size, void* d_ws, size_t ws_size,
                              hipStream_t stream)
{
    (void)in_sizes; (void)n_in; (void)out_size; (void)ws_size;

    const float* gf  = (const float*)d_in[0];
    const float* lf  = (const float*)d_in[1];
    const float* tf  = (const float*)d_in[2];
    const float* Wl1 = (const float*)d_in[3];  const float* bl1 = (const float*)d_in[4];
    const float* Wl2 = (const float*)d_in[5];  const float* bl2 = (const float*)d_in[6];
    const float* Wg  = (const float*)d_in[7];  const float* bg  = (const float*)d_in[8];
    const float* Wgq = (const float*)d_in[9];  const float* bgq = (const float*)d_in[10];
    const float* Wgk = (const float*)d_in[11]; const float* bgk = (const float*)d_in[12];
    const float* Wgv = (const float*)d_in[13]; const float* bgv = (const float*)d_in[14];
    const float* Wpq = (const float*)d_in[15]; const float* bpq = (const float*)d_in[16];
    const float* bpk = (const float*)d_in[18];
    const float* bpv = (const float*)d_in[20];
    const float* bd  = (const float*)d_in[22];
    const float* bm1 = (const float*)d_in[24];
    const float* bm2 = (const float*)d_in[26];
    const float* Wml = (const float*)d_in[27]; const float* bml = (const float*)d_in[28];

    const float C1 = 0.18033688011112042f;     // log2(e)/8, folded into pq/gq

    u16* ws = (u16*)d_ws;
    const size_t U = (size_t)Mn * Dn;          // 4,194,304 elems (8 MiB bf16)
    u16* S[9];
    for (int i = 0; i < 9; ++i) S[i] = ws + (size_t)i * U;
    u16* wtb = ws + 9 * U;

    const int sq = 65536;
    u16* Wpqt = wtb + 0*sq;  u16* Wgqt = wtb + 1*sq;  u16* Wgkt = wtb + 2*sq;  u16* Wgvt = wtb + 3*sq;
    u16* Wpkt = wtb + 4*sq;  u16* Wpvt = wtb + 5*sq;  u16* Wdt  = wtb + 6*sq;  u16* Wmlt = wtb + 7*sq;
    u16* Wm1t  = wtb + 524288;             // [1024][256] (transposed)
    u16* Wm2t  = wtb + 786432;             // [256][1024] (transposed)
    u16* Wl1rm = wtb + 1048576;
    u16* Wl2rm = wtb + 1114112;
    u16* Wgrm  = wtb + 1179648;
    u16* Wcpqt = wtb + 1245184;            // combined (W1@W2)^T bf16, 4x
    u16* Wcgqt = wtb + 1310720;
    u16* Wcgkt = wtb + 1376256;
    u16* Wcgvt = wtb + 1441792;
    float* fb  = (float*)(wtb + 1507328);  // biases: 4x256 @0, zero @1024

    // --- prep: input cvt + weight cvt + bias-combine, one launch
    WtArgs wa;
    const float* wsrc[13] = {Wpq, Wgq, Wgk, Wgv, (const float*)d_in[17], (const float*)d_in[19],
                             (const float*)d_in[21], Wml,
                             (const float*)d_in[23], (const float*)d_in[25], Wl1, Wl2, Wg};
    const int wdst[13] = {0, sq, 2*sq, 3*sq, 4*sq, 5*sq, 6*sq, 7*sq, 524288, 786432,
                          1048576, 1114112, 1179648};
    for (int i = 0; i < 13; ++i){
        wa.src[i] = wsrc[i];
        wa.kdim[i] = 256; wa.ndim[i] = 256;
        wa.dstoff[i] = wdst[i];
        wa.rm[i] = (i >= 10);
    }
    wa.ndim[8] = 1024;                 // Wm1 [256][1024] -> T [1024][256]
    wa.kdim[9] = 1024;                 // Wm2 [1024][256] -> T [256][1024]
    int acc_t = 0;
    for (int i = 0; i < 13; ++i){
        wa.t0[i] = acc_t;
        acc_t += (wa.ndim[i] >> 5) * (wa.kdim[i] >> 5);
    }
    BcArgs bc;
    bc.W2[0] = Wpq; bc.W2[1] = Wgq; bc.W2[2] = Wgk; bc.W2[3] = Wgv;
    bc.b1[0] = bl1; bc.b1[1] = bg;  bc.b1[2] = bl2; bc.b1[3] = bl2;
    bc.b2[0] = bpq; bc.b2[1] = bgq; bc.b2[2] = bgk; bc.b2[3] = bgv;
    bc.off[0] = 0; bc.off[1] = 256; bc.off[2] = 512; bc.off[3] = 768;
    bc.fb = fb; bc.bc0 = 6144 + acc_t;
    prep_k<<<dim3(6144 + acc_t + 4), 256, 0, stream>>>(lf, gf, tf, S[0], S[1], S[2], wa, wtb, bc);

    auto GN = [&](const Grp& g, int ng, int M, int N, int K, int act, int of32){
        dim3 gr(N / 128, M / 64, ng);
        if (act)        gemm_k<1,0><<<gr, 256, 0, stream>>>(g, N, K);
        else if (of32)  gemm_k<0,1><<<gr, 256, 0, stream>>>(g, N, K);
        else            gemm_k<0,0><<<gr, 256, 0, stream>>>(g, N, K);
    };
    auto G1 = [&](const u16* A, const u16* Wt_, const float* b, void* C, int M, int N, int K,
                  float sc, int act, int of32){
        Grp g{};
        g.A[0] = A; g.Wt[0] = Wt_; g.bias[0] = b; g.C[0] = C; g.scale[0] = sc;
        GN(g, 1, M, N, K, act, of32);
    };

    // --- mini grouped GEMM: Wc^T = W2^T @ W1^T  (M=256, 32 blocks)
    {
        Grp g{};
        g.A[0] = Wpqt; g.Wt[0] = Wl1rm; g.bias[0] = fb + 1024; g.C[0] = Wcpqt; g.scale[0] = 1.f;
        g.A[1] = Wgqt; g.Wt[1] = Wgrm;  g.bias[1] = fb + 1024; g.C[1] = Wcgqt; g.scale[1] = 1.f;
        g.A[2] = Wgkt; g.Wt[2] = Wl2rm; g.bias[2] = fb + 1024; g.C[2] = Wcgkt; g.scale[2] = 1.f;
        g.A[3] = Wgvt; g.Wt[3] = Wl2rm; g.bias[3] = fb + 1024; g.C[3] = Wcgvt; g.scale[3] = 1.f;
        GN(g, 4, 256, 256, 256, 0, 0);
    }

    // --- all 6 projections in ONE grouped launch (direct from raw inputs)
    {
        Grp g{};
        g.A[0] = S[0]; g.Wt[0] = Wcpqt; g.bias[0] = fb + 0;   g.C[0] = S[3]; g.scale[0] = C1;  // pq~
        g.A[1] = S[1]; g.Wt[1] = Wcgqt; g.bias[1] = fb + 256; g.C[1] = S[6]; g.scale[1] = C1;  // gq~
        g.A[2] = S[0]; g.Wt[2] = Wcgkt; g.bias[2] = fb + 512; g.C[2] = S[7]; g.scale[2] = 1.f; // gk
        g.A[3] = S[0]; g.Wt[3] = Wcgvt; g.bias[3] = fb + 768; g.C[3] = S[8]; g.scale[3] = 1.f; // gv
        g.A[4] = S[2]; g.Wt[4] = Wpkt;  g.bias[4] = bpk;      g.C[4] = S[4]; g.scale[4] = 1.f; // pk
        g.A[5] = S[2]; g.Wt[5] = Wpvt;  g.bias[5] = bpv;      g.C[5] = S[5]; g.scale[5] = 1.f; // pv
        GN(g, 6, Mn, 256, 256, 0, 0);
    }

    // --- attention: vsum = attn(pq,pk,pv) + gv ; ctx = attn(gq,gk,vsum)
    attn_k<1><<<dim3(256), 512, 0, stream>>>(S[3], S[4], S[5], S[0], S[8]);
    attn_k<0><<<dim3(256), 512, 0, stream>>>(S[6], S[7], S[0], S[1], nullptr);

    // --- output projection + MLP (unfused tail: numerics-safe)
    G1(S[1], Wdt,  bd,  S[2],  Mn, 256,  256,  1.f, 0, 0);  // out1
    G1(S[2], Wm1t, bm1, S[3],  Mn, 1024, 256,  1.f, 1, 0);  // hid = gelu(...), spans S3..S6
    G1(S[3], Wm2t, bm2, S[7],  Mn, 256,  1024, 1.f, 0, 0);  // out2
    G1(S[7], Wmlt, bml, d_out, Mn, 256,  256,  1.f, 0, 1);  // final (fp32 out)
}

// Round 11
// 232.684 us; speedup vs baseline: 1.2789x; 1.0333x over previous
//
#include <hip/hip_runtime.h>
#include <math.h>

#define Bn 8
#define Sn 2048
#define Dn 256
#define Hn 4
#define DHn 64
#define Mn (Bn*Sn)   // 16384 rows

typedef short bf16x8 __attribute__((ext_vector_type(8)));
typedef float f32x2  __attribute__((ext_vector_type(2)));
typedef float f32x4  __attribute__((ext_vector_type(4)));
typedef float f32x16 __attribute__((ext_vector_type(16)));
typedef int   i32x4  __attribute__((ext_vector_type(4)));
typedef unsigned short u16;
typedef unsigned int   u32;
typedef unsigned long long u64;

#if defined(__has_builtin)
#if __has_builtin(__builtin_amdgcn_global_load_lds)
#define HAVE_GLL 1
#endif
#if __has_builtin(__builtin_amdgcn_permlane32_swap)
#define HAVE_PLS 1
#endif
#endif
#ifndef HAVE_GLL
#define HAVE_GLL 0
#endif
#ifndef HAVE_PLS
#define HAVE_PLS 0
#endif

// ---------------------------------------------------------------------------
// helpers
// ---------------------------------------------------------------------------
__device__ __forceinline__ u16 f2b(float f){
    u32 u = __float_as_uint(f);
    u32 r = (u + 0x7fffu + ((u >> 16) & 1u)) >> 16;
    return (u16)r;
}
__device__ __forceinline__ float b2f(u16 h){ return __uint_as_float(((u32)h) << 16); }
__device__ __forceinline__ u32 cvtpk(float lo, float hi){
    u32 r;
    asm("v_cvt_pk_bf16_f32 %0, %1, %2" : "=v"(r) : "v"(lo), "v"(hi));
    return r;
}

// gelu(x) = x - x / (exp2(K1*x + K2*x^3) + 1)   [tanh form, exp2 domain]
__device__ __forceinline__ float gelu_f(float x){
    const float K1 = 2.3021143113f;      // 2*log2(e)*sqrt(2/pi)
    const float K2 = 0.1029390163f;      // K1 * 0.044715
    float x2 = x * x;
    float arg = fmaf(x2 * x, K2, x * K1);
    float e = exp2f(arg);
    float r = __builtin_amdgcn_rcpf(e + 1.0f);
    return x - x * r;
}

// ---------------------------------------------------------------------------
// prep: weight cvt (transpose or row-major) + bias-combine (last 4 blocks).
// Input fp32->bf16 cvt is GONE: the projection GEMM reads fp32 A directly.
// ---------------------------------------------------------------------------
struct WtArgs {
    const float* src[13];
    int kdim[13], ndim[13], dstoff[13], t0[13], rm[13];
};
struct BcArgs {
    const float* W2[4];
    const float* b1[4];
    const float* b2[4];
    int off[4];
    float* fb;
    int bc0;
};

__global__ __launch_bounds__(256) void prep_k(WtArgs a, u16* __restrict__ dst, BcArgs bc)
{
    __shared__ float tile[32][33];
    int bx = blockIdx.x;
    if (bx >= bc.bc0){
        int p = bx - bc.bc0, aa = threadIdx.x;
        const float* W2 = bc.W2[p];
        const float* b1 = bc.b1[p];
        const float* b2 = bc.b2[p];
        float s = b2[aa];
        for (int j = 0; j < 256; ++j) s = fmaf(b1[j], W2[(size_t)j*256 + aa], s);
        bc.fb[bc.off[p] + aa] = s;
        if (p == 0) bc.fb[1024 + aa] = 0.f;
        return;
    }
    int tb = bx;
    int wi = 0;
    #pragma unroll
    for (int i = 1; i < 13; ++i) if (tb >= a.t0[i]) wi = i;
    int tt = tb - a.t0[wi];
    int N = a.ndim[wi], K = a.kdim[wi];
    int ntn = N >> 5;
    int tn = tt % ntn, tk = tt / ntn;
    int n0 = tn * 32, k0 = tk * 32;
    const float* src = a.src[wi];
    u16* out = dst + a.dstoff[wi];
    int r = threadIdx.x >> 5, c = threadIdx.x & 31;
    if (a.rm[wi]){
        #pragma unroll
        for (int rr = 0; rr < 4; ++rr){
            size_t idx = (size_t)(k0 + r*4 + rr) * N + n0 + c;
            out[idx] = f2b(src[idx]);
        }
        return;
    }
    #pragma unroll
    for (int rr = 0; rr < 4; ++rr)
        tile[r*4+rr][c] = src[(size_t)(k0 + r*4 + rr) * N + n0 + c];
    __syncthreads();
    #pragma unroll
    for (int rr = 0; rr < 4; ++rr)
        out[(size_t)(n0 + r*4 + rr) * K + k0 + c] = f2b(tile[c][r*4+rr]);
}

// ---------------------------------------------------------------------------
// GEMM (grouped, bf16 A): C = act((A @ W + bias) * scale). Wt bf16 [N,K].
// 64x128 tile, BK=32, 4 waves, 2-phase dbuf LDS, counted vmcnt(3), GLL w16.
// ---------------------------------------------------------------------------
struct Grp {
    const u16* A[6];
    const u16* Wt[6];
    const float* bias[6];
    void* C[6];
    float scale[6];
};

template<int ACT, int OUTF32>
__global__ __launch_bounds__(256, 4) void gemm_k(Grp g, int N, int K)
{
    const u32 gx = gridDim.x, gy = gridDim.y;
    const u32 lgx = (u32)__builtin_ctz(gx);
    const u32 lgy = (u32)__builtin_ctz(gy);
    const u32 total = gx * gy * gridDim.z;
    const u32 lid = (blockIdx.z * gy + blockIdx.y) * gx + blockIdx.x;
    const u32 nl = (lid & 7) * (total >> 3) + (lid >> 3);
    const u32 bz = nl >> (lgx + lgy);
    const u32 by = (nl >> lgx) & (gy - 1);
    const u32 bx = nl & (gx - 1);

    const u16* __restrict__ A   = g.A[bz];
    const u16* __restrict__ Wt  = g.Wt[bz];
    const float* __restrict__ bias = g.bias[bz];
    void* __restrict__ Cv = g.C[bz];
    const float scale = g.scale[bz];

    __shared__ u16 sm[2][6144];
    const int tid = threadIdx.x;
    const int w = tid >> 6, lane = tid & 63;
    const int l15 = lane & 15, l4 = lane >> 4;
    const int wr = w & 1, wc = w >> 1;
    const int bm = by << 6, bn = bx << 7;
    const int xq = l4 ^ ((lane >> 1) & 3);

    f32x4 acc[4][2];
    #pragma unroll
    for (int nf = 0; nf < 4; ++nf)
        #pragma unroll
        for (int mf = 0; mf < 2; ++mf){
            acc[nf][mf][0]=0.f; acc[nf][mf][1]=0.f; acc[nf][mf][2]=0.f; acc[nf][mf][3]=0.f;
        }

    auto STAGE = [&](int buf, int kt){
        #pragma unroll
        for (int j = 0; j < 3; ++j){
            int ch = w*192 + j*64 + lane;
            int isB = ch >= 256;
            int cc  = isB ? ch - 256 : ch;
            int row = cc >> 2, q = cc & 3;
            int qs  = q ^ ((row >> 1) & 3);
            const u16* src = isB ? (Wt + (size_t)(bn + row) * K + kt + qs*8)
                                 : (A  + (size_t)(bm + row) * K + kt + qs*8);
#if HAVE_GLL
            u16* lb = &sm[buf][(size_t)(w*192 + j*64) * 8];
            __builtin_amdgcn_global_load_lds((const __attribute__((address_space(1))) void*)src,
                                             (__attribute__((address_space(3))) void*)lb, 16, 0, 0);
#else
            *(i32x4*)&sm[buf][(size_t)ch * 8] = *(const i32x4*)src;
#endif
        }
    };

    STAGE(0, 0);
    const int nk = K >> 5;
    for (int t = 0; t < nk; ++t){
        const int cur = t & 1;
        if (t + 1 < nk){
            STAGE(cur ^ 1, (t + 1) << 5);
#if HAVE_GLL
            asm volatile("s_waitcnt vmcnt(3)" ::: "memory");
#endif
        } else {
#if HAVE_GLL
            asm volatile("s_waitcnt vmcnt(0)" ::: "memory");
#endif
        }
        __builtin_amdgcn_s_barrier();
        asm volatile("" ::: "memory");

        const u16* As = sm[cur];
        const u16* Bs = sm[cur] + 2048;
        bf16x8 wf[4], af[2];
        #pragma unroll
        for (int nf = 0; nf < 4; ++nf)
            wf[nf] = *(const bf16x8*)(Bs + (size_t)(wc*64 + nf*16 + l15) * 32 + xq*8);
        #pragma unroll
        for (int mf = 0; mf < 2; ++mf)
            af[mf] = *(const bf16x8*)(As + (size_t)(wr*32 + mf*16 + l15) * 32 + xq*8);
        __builtin_amdgcn_s_setprio(1);
        #pragma unroll
        for (int nf = 0; nf < 4; ++nf)
            #pragma unroll
            for (int mf = 0; mf < 2; ++mf)
                acc[nf][mf] = __builtin_amdgcn_mfma_f32_16x16x32_bf16(wf[nf], af[mf], acc[nf][mf], 0, 0, 0);
        __builtin_amdgcn_s_setprio(0);

        asm volatile("" ::: "memory");
        __builtin_amdgcn_s_barrier();
    }

    #pragma unroll
    for (int nf = 0; nf < 4; ++nf){
        const int n0 = bn + wc*64 + nf*16 + l4*4;
        float4 b4 = *(const float4*)(bias + n0);
        #pragma unroll
        for (int mf = 0; mf < 2; ++mf){
            const int m = bm + wr*32 + mf*16 + l15;
            float r0 = (acc[nf][mf][0] + b4.x) * scale;
            float r1 = (acc[nf][mf][1] + b4.y) * scale;
            float r2 = (acc[nf][mf][2] + b4.z) * scale;
            float r3 = (acc[nf][mf][3] + b4.w) * scale;
            if (ACT){ r0 = gelu_f(r0); r1 = gelu_f(r1); r2 = gelu_f(r2); r3 = gelu_f(r3); }
            if (OUTF32){
                float4 o; o.x = r0; o.y = r1; o.z = r2; o.w = r3;
                *(float4*)((float*)Cv + (size_t)m * N + n0) = o;
            } else {
                u64 p = (u64)cvtpk(r0, r1) | ((u64)cvtpk(r2, r3) << 32);
                *(u64*)((u16*)Cv + (size_t)m * N + n0) = p;
            }
        }
    }
}

// ---------------------------------------------------------------------------
// GEMM (grouped, FP32 A): identical tiling/layout/swizzle; A is fp32 and is
// reg-staged (issue-early loads, cvt_pk + ds_write AFTER the MFMA phase —
// write-late, T14). B stays GLL with counted vmcnt(4). Output bf16, no act.
// Eliminates the separate input fp32->bf16 conversion pass.
// ---------------------------------------------------------------------------
struct Grp32 {
    const float* A[6];
    const u16* Wt[6];
    const float* bias[6];
    void* C[6];
    float scale[6];
};

__global__ __launch_bounds__(256, 4) void gemm32_k(Grp32 g, int N, int K)
{
    const u32 gx = gridDim.x, gy = gridDim.y;
    const u32 lgx = (u32)__builtin_ctz(gx);
    const u32 lgy = (u32)__builtin_ctz(gy);
    const u32 total = gx * gy * gridDim.z;
    const u32 lid = (blockIdx.z * gy + blockIdx.y) * gx + blockIdx.x;
    const u32 nl = (lid & 7) * (total >> 3) + (lid >> 3);
    const u32 bz = nl >> (lgx + lgy);
    const u32 by = (nl >> lgx) & (gy - 1);
    const u32 bx = nl & (gx - 1);

    const float* __restrict__ A = g.A[bz];
    const u16* __restrict__ Wt  = g.Wt[bz];
    const float* __restrict__ bias = g.bias[bz];
    void* __restrict__ Cv = g.C[bz];
    const float scale = g.scale[bz];

    __shared__ u16 sm[2][6144];           // A [64][32] @0, B [128][32] @2048
    const int tid = threadIdx.x;
    const int w = tid >> 6, lane = tid & 63;
    const int l15 = lane & 15, l4 = lane >> 4;
    const int wr = w & 1, wc = w >> 1;
    const int bm = by << 6, bn = bx << 7;
    const int xq = l4 ^ ((lane >> 1) & 3);

    f32x4 acc[4][2];
    #pragma unroll
    for (int nf = 0; nf < 4; ++nf)
        #pragma unroll
        for (int mf = 0; mf < 2; ++mf){
            acc[nf][mf][0]=0.f; acc[nf][mf][1]=0.f; acc[nf][mf][2]=0.f; acc[nf][mf][3]=0.f;
        }

    // A: one bf16-chunk per thread (chunk tid): row=tid>>2, q=tid&3, src-swizzled
    const int arow = tid >> 2, aq = tid & 3;
    const int aqs = aq ^ ((arow >> 1) & 3);
    const float* Ab = A + (size_t)(bm + arow) * K + aqs*8;
    float4 a0r, a1r;
    auto A_ISSUE = [&](int kt){
        a0r = *(const float4*)(Ab + kt);
        a1r = *(const float4*)(Ab + kt + 4);
    };
    auto A_WRITE = [&](int buf){
        i32x4 o;
        o[0] = (int)cvtpk(a0r.x, a0r.y); o[1] = (int)cvtpk(a0r.z, a0r.w);
        o[2] = (int)cvtpk(a1r.x, a1r.y); o[3] = (int)cvtpk(a1r.z, a1r.w);
        *(i32x4*)&sm[buf][(size_t)tid * 8] = o;
    };
    auto B_STAGE = [&](int buf, int kt){
        #pragma unroll
        for (int j = 0; j < 2; ++j){
            int ch = w*128 + j*64 + lane;     // 0..511
            int row = ch >> 2, q = ch & 3;
            int qs  = q ^ ((row >> 1) & 3);
            const u16* src = Wt + (size_t)(bn + row) * K + kt + qs*8;
#if HAVE_GLL
            u16* lb = &sm[buf][2048 + (size_t)(w*128 + j*64) * 8];
            __builtin_amdgcn_global_load_lds((const __attribute__((address_space(1))) void*)src,
                                             (__attribute__((address_space(3))) void*)lb, 16, 0, 0);
#else
            *(i32x4*)&sm[buf][2048 + (size_t)ch * 8] = *(const i32x4*)src;
#endif
        }
    };

    // prologue
    A_ISSUE(0);
    B_STAGE(0, 0);
    A_WRITE(0);
    __syncthreads();

    const int nk = K >> 5;
    for (int t = 0; t < nk; ++t){
        const int cur = t & 1;
        if (t + 1 < nk){
            A_ISSUE((t + 1) << 5);
            B_STAGE(cur ^ 1, (t + 1) << 5);
#if HAVE_GLL
            asm volatile("s_waitcnt vmcnt(4)" ::: "memory");  // prev B done; next A+B in flight
#endif
        } else {
#if HAVE_GLL
            asm volatile("s_waitcnt vmcnt(0)" ::: "memory");
#endif
        }
        __builtin_amdgcn_s_barrier();
        asm volatile("" ::: "memory");

        const u16* As = sm[cur];
        const u16* Bs = sm[cur] + 2048;
        bf16x8 wf[4], af[2];
        #pragma unroll
        for (int nf = 0; nf < 4; ++nf)
            wf[nf] = *(const bf16x8*)(Bs + (size_t)(wc*64 + nf*16 + l15) * 32 + xq*8);
        #pragma unroll
        for (int mf = 0; mf < 2; ++mf)
            af[mf] = *(const bf16x8*)(As + (size_t)(wr*32 + mf*16 + l15) * 32 + xq*8);
        __builtin_amdgcn_s_setprio(1);
        #pragma unroll
        for (int nf = 0; nf < 4; ++nf)
            #pragma unroll
            for (int mf = 0; mf < 2; ++mf)
                acc[nf][mf] = __builtin_amdgcn_mfma_f32_16x16x32_bf16(wf[nf], af[mf], acc[nf][mf], 0, 0, 0);
        __builtin_amdgcn_s_setprio(0);

        if (t + 1 < nk) A_WRITE(cur ^ 1);    // write-late into the other buffer
        asm volatile("" ::: "memory");
        asm volatile("s_waitcnt lgkmcnt(0)" ::: "memory");
        __builtin_amdgcn_s_barrier();
    }

    #pragma unroll
    for (int nf = 0; nf < 4; ++nf){
        const int n0 = bn + wc*64 + nf*16 + l4*4;
        float4 b4 = *(const float4*)(bias + n0);
        #pragma unroll
        for (int mf = 0; mf < 2; ++mf){
            const int m = bm + wr*32 + mf*16 + l15;
            float r0 = (acc[nf][mf][0] + b4.x) * scale;
            float r1 = (acc[nf][mf][1] + b4.y) * scale;
            float r2 = (acc[nf][mf][2] + b4.z) * scale;
            float r3 = (acc[nf][mf][3] + b4.w) * scale;
            u64 p = (u64)cvtpk(r0, r1) | ((u64)cvtpk(r2, r3) << 32);
            *(u64*)((u16*)Cv + (size_t)m * N + n0) = p;
        }
    }
}

// ---------------------------------------------------------------------------
// bf16 MFMA flash attention, KV tile = 128 (two 64-key halves per barrier).
// r6 structure otherwise: 4 waves x 32 q rows (128 q/block), grid 512 =
// 2 blocks/CU; K and V^T double-buffered [2][half][64x72] padded LDS,
// reg-staged (T14 issue-early/write-late), ONE barrier per 128-key tile
// (half the barrier/batch overhead of r6). Fixed m=0 softmax (Q pre-scaled
// by log2e/8 in producer GEMM) — math sequence bit-identical to r6.
// ---------------------------------------------------------------------------
template<int FUSE>
__global__ __launch_bounds__(256, 2) void attn_k(const u16* __restrict__ Q, const u16* __restrict__ Kp,
                                                 const u16* __restrict__ Vp, u16* __restrict__ O,
                                                 const u16* __restrict__ ADD)
{
    __shared__ u16 Kl[2][2][4608];       // [buf][half][64*72]
    __shared__ u16 Vt[2][2][4608];       // [buf][half][d*72 + k]

    const int tid = threadIdx.x;
    const int w = tid >> 6, lane = tid & 63;
    const int c31 = lane & 31, h = lane >> 5;

    // XCD-chunked swizzle: 512 blocks -> each XCD owns 4 heads x 16 q-blocks
    const int lid = blockIdx.x;
    const int nl = (lid & 7) * 64 + (lid >> 3);
    const int bh = nl >> 4;
    const int qb = (nl & 15) << 7;
    const size_t hb = (size_t)(bh >> 2) * Sn * Dn + (size_t)(bh & 3) * DHn;
    const int qrow = qb + w*32 + c31;

    bf16x8 qf[4];
    #pragma unroll
    for (int kc = 0; kc < 4; ++kc)
        qf[kc] = *(const bf16x8*)(Q + hb + (size_t)qrow * Dn + kc*16 + h*8);

    f32x16 ot0, ot1;
    #pragma unroll
    for (int r = 0; r < 16; ++r){ ot0[r] = 0.f; ot1[r] = 0.f; }
    float ll = 0.f;

    // per-half LDS read offsets (u16 units, [72]-padded rows)
    int koff0[4], koff1[4];
    #pragma unroll
    for (int kc = 0; kc < 4; ++kc){
        koff0[kc] = c31*72        + kc*16 + h*8;
        koff1[kc] = (32 + c31)*72 + kc*16 + h*8;
    }

    // K staging: row = tid>>1 (0..127), 4x16B chunks at elems kq+{0,16,32,48}
    const int krow = tid >> 1, kq = (tid & 1) * 8;
    const int khalf = krow >> 6, krow63 = krow & 63;
    // V staging: keys vk0..vk0+3, dim blocks vd0 and vd0+32
    const int vk0 = (tid & 31) * 4, vd0 = (tid >> 5) * 4;
    const int vhalf = vk0 >> 6, vk63 = vk0 & 63;
    const u32 SEL_LO = 0x05040100u, SEL_HI = 0x07060302u;

    i32x4 kr[4];
    u64 va_[4], vb_[4];
    auto LOADKV = [&](int kt2){
        const u16* kb = Kp + hb + (size_t)(kt2 + krow) * Dn + kq;
        kr[0] = *(const i32x4*)(kb);
        kr[1] = *(const i32x4*)(kb + 16);
        kr[2] = *(const i32x4*)(kb + 32);
        kr[3] = *(const i32x4*)(kb + 48);
        const u16* vb = Vp + hb + (size_t)(kt2 + vk0) * Dn + vd0;
        va_[0] = *(const u64*)(vb);             va_[1] = *(const u64*)(vb + Dn);
        va_[2] = *(const u64*)(vb + 2*Dn);      va_[3] = *(const u64*)(vb + 3*Dn);
        vb_[0] = *(const u64*)(vb + 32);        vb_[1] = *(const u64*)(vb + Dn + 32);
        vb_[2] = *(const u64*)(vb + 2*Dn + 32); vb_[3] = *(const u64*)(vb + 3*Dn + 32);
    };
    auto WRITEKV = [&](int buf){
        u16* kd = &Kl[buf][khalf][(size_t)krow63*72 + kq];
        *(i32x4*)(kd)      = kr[0];
        *(i32x4*)(kd + 16) = kr[1];
        *(i32x4*)(kd + 32) = kr[2];
        *(i32x4*)(kd + 48) = kr[3];
        {   // V block A: dims vd0..vd0+3
            u32 a0 = (u32)va_[0], a1 = (u32)va_[1], a2 = (u32)va_[2], a3 = (u32)va_[3];
            u32 b0 = (u32)(va_[0] >> 32), b1 = (u32)(va_[1] >> 32), b2 = (u32)(va_[2] >> 32), b3 = (u32)(va_[3] >> 32);
            u64 wd0 = (u64)__builtin_amdgcn_perm(a1, a0, SEL_LO) | ((u64)__builtin_amdgcn_perm(a3, a2, SEL_LO) << 32);
            u64 wd1 = (u64)__builtin_amdgcn_perm(a1, a0, SEL_HI) | ((u64)__builtin_amdgcn_perm(a3, a2, SEL_HI) << 32);
            u64 wd2 = (u64)__builtin_amdgcn_perm(b1, b0, SEL_LO) | ((u64)__builtin_amdgcn_perm(b3, b2, SEL_LO) << 32);
            u64 wd3 = (u64)__builtin_amdgcn_perm(b1, b0, SEL_HI) | ((u64)__builtin_amdgcn_perm(b3, b2, SEL_HI) << 32);
            *(u64*)&Vt[buf][vhalf][(size_t)(vd0 + 0)*72 + vk63] = wd0;
            *(u64*)&Vt[buf][vhalf][(size_t)(vd0 + 1)*72 + vk63] = wd1;
            *(u64*)&Vt[buf][vhalf][(size_t)(vd0 + 2)*72 + vk63] = wd2;
            *(u64*)&Vt[buf][vhalf][(size_t)(vd0 + 3)*72 + vk63] = wd3;
        }
        {   // V block B: dims vd0+32..vd0+35
            u32 a0 = (u32)vb_[0], a1 = (u32)vb_[1], a2 = (u32)vb_[2], a3 = (u32)vb_[3];
            u32 b0 = (u32)(vb_[0] >> 32), b1 = (u32)(vb_[1] >> 32), b2 = (u32)(vb_[2] >> 32), b3 = (u32)(vb_[3] >> 32);
            u64 wd0 = (u64)__builtin_amdgcn_perm(a1, a0, SEL_LO) | ((u64)__builtin_amdgcn_perm(a3, a2, SEL_LO) << 32);
            u64 wd1 = (u64)__builtin_amdgcn_perm(a1, a0, SEL_HI) | ((u64)__builtin_amdgcn_perm(a3, a2, SEL_HI) << 32);
            u64 wd2 = (u64)__builtin_amdgcn_perm(b1, b0, SEL_LO) | ((u64)__builtin_amdgcn_perm(b3, b2, SEL_LO) << 32);
            u64 wd3 = (u64)__builtin_amdgcn_perm(b1, b0, SEL_HI) | ((u64)__builtin_amdgcn_perm(b3, b2, SEL_HI) << 32);
            *(u64*)&Vt[buf][vhalf][(size_t)(vd0 + 32)*72 + vk63] = wd0;
            *(u64*)&Vt[buf][vhalf][(size_t)(vd0 + 33)*72 + vk63] = wd1;
            *(u64*)&Vt[buf][vhalf][(size_t)(vd0 + 34)*72 + vk63] = wd2;
            *(u64*)&Vt[buf][vhalf][(size_t)(vd0 + 35)*72 + vk63] = wd3;
        }
    };

    // prologue
    LOADKV(0);
    WRITEKV(0);
    __syncthreads();

    for (int t = 0; t < 16; ++t){
        const int c = t & 1;
        const bool more = (t < 15);
        if (more) LOADKV((t + 1) << 7);      // T14: issue early, two halves of cover

        #pragma unroll
        for (int hh = 0; hh < 2; ++hh){
            // --- S^T = K @ Q^T  (per lane: 32 pre-scaled scores for q = c31)
            f32x16 s0, s1;
            #pragma unroll
            for (int r = 0; r < 16; ++r){ s0[r] = 0.f; s1[r] = 0.f; }
            __builtin_amdgcn_s_setprio(1);
            #pragma unroll
            for (int kc = 0; kc < 4; ++kc){
                bf16x8 k0 = *(const bf16x8*)&Kl[c][hh][koff0[kc]];
                bf16x8 k1 = *(const bf16x8*)&Kl[c][hh][koff1[kc]];
                s0 = __builtin_amdgcn_mfma_f32_32x32x16_bf16(k0, qf[kc], s0, 0, 0, 0);
                s1 = __builtin_amdgcn_mfma_f32_32x32x16_bf16(k1, qf[kc], s1, 0, 0, 0);
            }
            __builtin_amdgcn_s_setprio(0);

            // --- softmax numerator, fixed m=0: p = exp2(s); packed-pair sums
            f32x2 pp0[8], pp1[8];
            f32x2 rv = {0.f, 0.f};
            #pragma unroll
            for (int r = 0; r < 8; ++r){
                pp0[r][0] = exp2f(s0[2*r]); pp0[r][1] = exp2f(s0[2*r+1]);
                pp1[r][0] = exp2f(s1[2*r]); pp1[r][1] = exp2f(s1[2*r+1]);
                rv += pp0[r];
                rv += pp1[r];
            }
            ll += rv[0] + rv[1];

            // --- pack P^T fragments (cvt_pk + permlane32_swap) and PV MFMA
            __builtin_amdgcn_s_setprio(1);
            #pragma unroll
            for (int kc = 0; kc < 4; ++kc){
                const int iA = 2*kc, iB = 2*kc + 1;
                u32 wA0, wA1, wB0, wB1;
                if (kc < 2){
                    wA0 = cvtpk(pp0[iA*2+0][0], pp0[iA*2+0][1]);
                    wA1 = cvtpk(pp0[iA*2+1][0], pp0[iA*2+1][1]);
                    wB0 = cvtpk(pp0[iB*2+0][0], pp0[iB*2+0][1]);
                    wB1 = cvtpk(pp0[iB*2+1][0], pp0[iB*2+1][1]);
                } else {
                    wA0 = cvtpk(pp1[(iA-4)*2+0][0], pp1[(iA-4)*2+0][1]);
                    wA1 = cvtpk(pp1[(iA-4)*2+1][0], pp1[(iA-4)*2+1][1]);
                    wB0 = cvtpk(pp1[(iB-4)*2+0][0], pp1[(iB-4)*2+0][1]);
                    wB1 = cvtpk(pp1[(iB-4)*2+1][0], pp1[(iB-4)*2+1][1]);
                }
                i32x4 pw;
#if HAVE_PLS
                {
                    auto r02 = __builtin_amdgcn_permlane32_swap((int)wA0, (int)wB0, false, false);
                    auto r13 = __builtin_amdgcn_permlane32_swap((int)wA1, (int)wB1, false, false);
                    pw[0] = r02[0]; pw[1] = r13[0]; pw[2] = r02[1]; pw[3] = r13[1];
                }
#else
                {
                    u32 s0v = h ? wA0 : wB0, s1v = h ? wA1 : wB1;
                    u32 g0 = (u32)__shfl_xor((int)s0v, 32);
                    u32 g1 = (u32)__shfl_xor((int)s1v, 32);
                    pw[0] = (int)(h ? g0 : wA0);
                    pw[1] = (int)(h ? g1 : wA1);
                    pw[2] = (int)(h ? wB0 : g0);
                    pw[3] = (int)(h ? wB1 : g1);
                }
#endif
                bf16x8 pb = *(bf16x8*)&pw;
                bf16x8 va  = *(const bf16x8*)&Vt[c][hh][koff0[kc]];
                bf16x8 vb2 = *(const bf16x8*)&Vt[c][hh][koff1[kc]];
                ot0 = __builtin_amdgcn_mfma_f32_32x32x16_bf16(va,  pb, ot0, 0, 0, 0);
                ot1 = __builtin_amdgcn_mfma_f32_32x32x16_bf16(vb2, pb, ot1, 0, 0, 0);
            }
            __builtin_amdgcn_s_setprio(0);
        }

        if (more) WRITEKV(c ^ 1);   // write-late; compiler waits vmcnt on the loads
        __syncthreads();            // one barrier per 128-key tile
    }

    // --- combine lane-halves, normalize, store (optional fused add)
    ll += __shfl_xor(ll, 32);
    float inv = 1.0f / ll;
    #pragma unroll
    for (int rg = 0; rg < 4; ++rg){
        int d0 = 8*rg + 4*h;
        float r0 = ot0[4*rg+0]*inv, r1 = ot0[4*rg+1]*inv, r2 = ot0[4*rg+2]*inv, r3 = ot0[4*rg+3]*inv;
        float x0 = ot1[4*rg+0]*inv, x1 = ot1[4*rg+1]*inv, x2 = ot1[4*rg+2]*inv, x3 = ot1[4*rg+3]*inv;
        if (FUSE){
            u64 ga = *(const u64*)&ADD[hb + (size_t)qrow * Dn + d0];
            u64 gb = *(const u64*)&ADD[hb + (size_t)qrow * Dn + 32 + d0];
            r0 += b2f((u16)ga);         r1 += b2f((u16)(ga >> 16));
            r2 += b2f((u16)(ga >> 32)); r3 += b2f((u16)(ga >> 48));
            x0 += b2f((u16)gb);         x1 += b2f((u16)(gb >> 16));
            x2 += b2f((u16)(gb >> 32)); x3 += b2f((u16)(gb >> 48));
        }
        *(u64*)&O[hb + (size_t)qrow * Dn + d0]      = (u64)cvtpk(r0, r1) | ((u64)cvtpk(r2, r3) << 32);
        *(u64*)&O[hb + (size_t)qrow * Dn + 32 + d0] = (u64)cvtpk(x0, x1) | ((u64)cvtpk(x2, x3) << 32);
    }
}

// ---------------------------------------------------------------------------
// Orchestration.
//   glb_ctx + plb_ctx = glb_probs @ (gv + plb_probs @ pv)       [attn fold]
//   pq = lf@(Wl1@Wpq)+bc, gq = gf@(Wg@Wgq)+bc, gk/gv = lf@(Wl2@Wg{k,v})+bc
//   projections read fp32 inputs directly (gemm32_k) — no input-cvt pass
// ---------------------------------------------------------------------------
extern "C" void kernel_launch(void* const* d_in, const int* in_sizes, int n_in,
                              void* d_out, int out_size, void* d_ws, size_t ws_size,
                              hipStream_t stream)
{
    (void)in_sizes; (void)n_in; (void)out_size; (void)ws_size;

    const float* gf  = (const float*)d_in[0];
    const float* lf  = (const float*)d_in[1];
    const float* tf  = (const float*)d_in[2];
    const float* Wl1 = (const float*)d_in[3];  const float* bl1 = (const float*)d_in[4];
    const float* Wl2 = (const float*)d_in[5];  const float* bl2 = (const float*)d_in[6];
    const float* Wg  = (const float*)d_in[7];  const float* bg  = (const float*)d_in[8];
    const float* Wgq = (const float*)d_in[9];  const float* bgq = (const float*)d_in[10];
    const float* Wgk = (const float*)d_in[11]; const float* bgk = (const float*)d_in[12];
    const float* Wgv = (const float*)d_in[13]; const float* bgv = (const float*)d_in[14];
    const float* Wpq = (const float*)d_in[15]; const float* bpq = (const float*)d_in[16];
    const float* bpk = (const float*)d_in[18];
    const float* bpv = (const float*)d_in[20];
    const float* bd  = (const float*)d_in[22];
    const float* bm1 = (const float*)d_in[24];
    const float* bm2 = (const float*)d_in[26];
    const float* Wml = (const float*)d_in[27]; const float* bml = (const float*)d_in[28];

    const float C1 = 0.18033688011112042f;     // log2(e)/8, folded into pq/gq

    u16* ws = (u16*)d_ws;
    const size_t U = (size_t)Mn * Dn;          // 4,194,304 elems (8 MiB bf16)
    u16* S[9];
    for (int i = 0; i < 9; ++i) S[i] = ws + (size_t)i * U;
    u16* wtb = ws + 9 * U;

    const int sq = 65536;
    u16* Wpqt = wtb + 0*sq;  u16* Wgqt = wtb + 1*sq;  u16* Wgkt = wtb + 2*sq;  u16* Wgvt = wtb + 3*sq;
    u16* Wpkt = wtb + 4*sq;  u16* Wpvt = wtb + 5*sq;  u16* Wdt  = wtb + 6*sq;  u16* Wmlt = wtb + 7*sq;
    u16* Wm1t  = wtb + 524288;             // [1024][256] (transposed)
    u16* Wm2t  = wtb + 786432;             // [256][1024] (transposed)
    u16* Wl1rm = wtb + 1048576;
    u16* Wl2rm = wtb + 1114112;
    u16* Wgrm  = wtb + 1179648;
    u16* Wcpqt = wtb + 1245184;            // combined (W1@W2)^T bf16, 4x
    u16* Wcgqt = wtb + 1310720;
    u16* Wcgkt = wtb + 1376256;
    u16* Wcgvt = wtb + 1441792;
    float* fb  = (float*)(wtb + 1507328);  // biases: 4x256 @0, zero @1024

    // --- prep: weight cvt + bias-combine, one launch (no input cvt)
    WtArgs wa;
    const float* wsrc[13] = {Wpq, Wgq, Wgk, Wgv, (const float*)d_in[17], (const float*)d_in[19],
                             (const float*)d_in[21], Wml,
                             (const float*)d_in[23], (const float*)d_in[25], Wl1, Wl2, Wg};
    const int wdst[13] = {0, sq, 2*sq, 3*sq, 4*sq, 5*sq, 6*sq, 7*sq, 524288, 786432,
                          1048576, 1114112, 1179648};
    for (int i = 0; i < 13; ++i){
        wa.src[i] = wsrc[i];
        wa.kdim[i] = 256; wa.ndim[i] = 256;
        wa.dstoff[i] = wdst[i];
        wa.rm[i] = (i >= 10);
    }
    wa.ndim[8] = 1024;                 // Wm1 [256][1024] -> T [1024][256]
    wa.kdim[9] = 1024;                 // Wm2 [1024][256] -> T [256][1024]
    int acc_t = 0;
    for (int i = 0; i < 13; ++i){
        wa.t0[i] = acc_t;
        acc_t += (wa.ndim[i] >> 5) * (wa.kdim[i] >> 5);
    }
    BcArgs bc;
    bc.W2[0] = Wpq; bc.W2[1] = Wgq; bc.W2[2] = Wgk; bc.W2[3] = Wgv;
    bc.b1[0] = bl1; bc.b1[1] = bg;  bc.b1[2] = bl2; bc.b1[3] = bl2;
    bc.b2[0] = bpq; bc.b2[1] = bgq; bc.b2[2] = bgk; bc.b2[3] = bgv;
    bc.off[0] = 0; bc.off[1] = 256; bc.off[2] = 512; bc.off[3] = 768;
    bc.fb = fb; bc.bc0 = acc_t;
    prep_k<<<dim3(acc_t + 4), 256, 0, stream>>>(wa, wtb, bc);

    auto GN = [&](const Grp& g, int ng, int M, int N, int K, int act, int of32){
        dim3 gr(N / 128, M / 64, ng);
        if (act)        gemm_k<1,0><<<gr, 256, 0, stream>>>(g, N, K);
        else if (of32)  gemm_k<0,1><<<gr, 256, 0, stream>>>(g, N, K);
        else            gemm_k<0,0><<<gr, 256, 0, stream>>>(g, N, K);
    };
    auto G1 = [&](const u16* A, const u16* Wt_, const float* b, void* C, int M, int N, int K,
                  float sc, int act, int of32){
        Grp g{};
        g.A[0] = A; g.Wt[0] = Wt_; g.bias[0] = b; g.C[0] = C; g.scale[0] = sc;
        GN(g, 1, M, N, K, act, of32);
    };

    // --- mini grouped GEMM: Wc^T = W2^T @ W1^T  (M=256, 32 blocks)
    {
        Grp g{};
        g.A[0] = Wpqt; g.Wt[0] = Wl1rm; g.bias[0] = fb + 1024; g.C[0] = Wcpqt; g.scale[0] = 1.f;
        g.A[1] = Wgqt; g.Wt[1] = Wgrm;  g.bias[1] = fb + 1024; g.C[1] = Wcgqt; g.scale[1] = 1.f;
        g.A[2] = Wgkt; g.Wt[2] = Wl2rm; g.bias[2] = fb + 1024; g.C[2] = Wcgkt; g.scale[2] = 1.f;
        g.A[3] = Wgvt; g.Wt[3] = Wl2rm; g.bias[3] = fb + 1024; g.C[3] = Wcgvt; g.scale[3] = 1.f;
        GN(g, 4, 256, 256, 256, 0, 0);
    }

    // --- all 6 projections in ONE grouped launch, reading fp32 inputs
    {
        Grp32 g{};
        g.A[0] = lf; g.Wt[0] = Wcpqt; g.bias[0] = fb + 0;   g.C[0] = S[3]; g.scale[0] = C1;  // pq~
        g.A[1] = gf; g.Wt[1] = Wcgqt; g.bias[1] = fb + 256; g.C[1] = S[6]; g.scale[1] = C1;  // gq~
        g.A[2] = lf; g.Wt[2] = Wcgkt; g.bias[2] = fb + 512; g.C[2] = S[7]; g.scale[2] = 1.f; // gk
        g.A[3] = lf; g.Wt[3] = Wcgvt; g.bias[3] = fb + 768; g.C[3] = S[8]; g.scale[3] = 1.f; // gv
        g.A[4] = tf; g.Wt[4] = Wpkt;  g.bias[4] = bpk;      g.C[4] = S[4]; g.scale[4] = 1.f; // pk
        g.A[5] = tf; g.Wt[5] = Wpvt;  g.bias[5] = bpv;      g.C[5] = S[5]; g.scale[5] = 1.f; // pv
        dim3 gr(2, Mn / 64, 6);
        gemm32_k<<<gr, 256, 0, stream>>>(g, 256, 256);
    }

    // --- attention: vsum = attn(pq,pk,pv) + gv ; ctx = attn(gq,gk,vsum)
    attn_k<1><<<dim3(512), 256, 0, stream>>>(S[3], S[4], S[5], S[0], S[8]);
    attn_k<0><<<dim3(512), 256, 0, stream>>>(S[6], S[7], S[0], S[1], nullptr);

    // --- output projection + MLP (unfused tail: numerics-safe)
    G1(S[1], Wdt,  bd,  S[2],  Mn, 256,  256,  1.f, 0, 0);  // out1
    G1(S[2], Wm1t, bm1, S[3],  Mn, 1024, 256,  1.f, 1, 0);  // hid = gelu(...), spans S3..S6
    G1(S[3], Wm2t, bm2, S[7],  Mn, 256,  1024, 1.f, 0, 0);  // out2
    G1(S[7], Wmlt, bml, d_out, Mn, 256,  256,  1.f, 0, 1);  // final (fp32 out)
}

// Round 12
// 218.308 us; speedup vs baseline: 1.3631x; 1.0659x over previous
//
#include <hip/hip_runtime.h>
#include <math.h>

#define Bn 8
#define Sn 2048
#define Dn 256
#define Hn 4
#define DHn 64
#define Mn (Bn*Sn)   // 16384 rows

typedef short bf16x8 __attribute__((ext_vector_type(8)));
typedef float f32x2  __attribute__((ext_vector_type(2)));
typedef float f32x4  __attribute__((ext_vector_type(4)));
typedef float f32x16 __attribute__((ext_vector_type(16)));
typedef int   i32x4  __attribute__((ext_vector_type(4)));
typedef unsigned short u16;
typedef unsigned int   u32;
typedef unsigned long long u64;

#if defined(__has_builtin)
#if __has_builtin(__builtin_amdgcn_global_load_lds)
#define HAVE_GLL 1
#endif
#if __has_builtin(__builtin_amdgcn_permlane32_swap)
#define HAVE_PLS 1
#endif
#endif
#ifndef HAVE_GLL
#define HAVE_GLL 0
#endif
#ifndef HAVE_PLS
#define HAVE_PLS 0
#endif

// ---------------------------------------------------------------------------
// helpers
// ---------------------------------------------------------------------------
__device__ __forceinline__ u16 f2b(float f){
    u32 u = __float_as_uint(f);
    u32 r = (u + 0x7fffu + ((u >> 16) & 1u)) >> 16;
    return (u16)r;
}
__device__ __forceinline__ float b2f(u16 h){ return __uint_as_float(((u32)h) << 16); }
__device__ __forceinline__ u32 cvtpk(float lo, float hi){
    u32 r;
    asm("v_cvt_pk_bf16_f32 %0, %1, %2" : "=v"(r) : "v"(lo), "v"(hi));
    return r;
}

// gelu(x) = x - x / (exp2(K1*x + K2*x^3) + 1)   [tanh form, exp2 domain]
__device__ __forceinline__ float gelu_f(float x){
    const float K1 = 2.3021143113f;      // 2*log2(e)*sqrt(2/pi)
    const float K2 = 0.1029390163f;      // K1 * 0.044715
    float x2 = x * x;
    float arg = fmaf(x2 * x, K2, x * K1);
    float e = exp2f(arg);
    float r = __builtin_amdgcn_rcpf(e + 1.0f);
    return x - x * r;
}

// ---------------------------------------------------------------------------
// prep: weight cvt (transpose or row-major) + bias-combine (last 4 blocks).
// ---------------------------------------------------------------------------
struct WtArgs {
    const float* src[13];
    int kdim[13], ndim[13], dstoff[13], t0[13], rm[13];
};
struct BcArgs {
    const float* W2[4];
    const float* b1[4];
    const float* b2[4];
    int off[4];
    float* fb;
    int bc0;
};

__global__ __launch_bounds__(256) void prep_k(WtArgs a, u16* __restrict__ dst, BcArgs bc)
{
    __shared__ float tile[32][33];
    int bx = blockIdx.x;
    if (bx >= bc.bc0){
        int p = bx - bc.bc0, aa = threadIdx.x;
        const float* W2 = bc.W2[p];
        const float* b1 = bc.b1[p];
        const float* b2 = bc.b2[p];
        float s = b2[aa];
        for (int j = 0; j < 256; ++j) s = fmaf(b1[j], W2[(size_t)j*256 + aa], s);
        bc.fb[bc.off[p] + aa] = s;
        if (p == 0) bc.fb[1024 + aa] = 0.f;
        return;
    }
    int tb = bx;
    int wi = 0;
    #pragma unroll
    for (int i = 1; i < 13; ++i) if (tb >= a.t0[i]) wi = i;
    int tt = tb - a.t0[wi];
    int N = a.ndim[wi], K = a.kdim[wi];
    int ntn = N >> 5;
    int tn = tt % ntn, tk = tt / ntn;
    int n0 = tn * 32, k0 = tk * 32;
    const float* src = a.src[wi];
    u16* out = dst + a.dstoff[wi];
    int r = threadIdx.x >> 5, c = threadIdx.x & 31;
    if (a.rm[wi]){
        #pragma unroll
        for (int rr = 0; rr < 4; ++rr){
            size_t idx = (size_t)(k0 + r*4 + rr) * N + n0 + c;
            out[idx] = f2b(src[idx]);
        }
        return;
    }
    #pragma unroll
    for (int rr = 0; rr < 4; ++rr)
        tile[r*4+rr][c] = src[(size_t)(k0 + r*4 + rr) * N + n0 + c];
    __syncthreads();
    #pragma unroll
    for (int rr = 0; rr < 4; ++rr)
        out[(size_t)(n0 + r*4 + rr) * K + k0 + c] = f2b(tile[c][r*4+rr]);
}

// ---------------------------------------------------------------------------
// GEMM (grouped, bf16 A): C = act((A @ W + bias) * scale). Wt bf16 [N,K].
// 64x128 tile, BK=32, 4 waves, 2-phase dbuf LDS, counted vmcnt(3), GLL w16.
// ---------------------------------------------------------------------------
struct Grp {
    const u16* A[6];
    const u16* Wt[6];
    const float* bias[6];
    void* C[6];
    float scale[6];
};

template<int ACT, int OUTF32>
__global__ __launch_bounds__(256, 4) void gemm_k(Grp g, int N, int K)
{
    const u32 gx = gridDim.x, gy = gridDim.y;
    const u32 lgx = (u32)__builtin_ctz(gx);
    const u32 lgy = (u32)__builtin_ctz(gy);
    const u32 total = gx * gy * gridDim.z;
    const u32 lid = (blockIdx.z * gy + blockIdx.y) * gx + blockIdx.x;
    const u32 nl = (lid & 7) * (total >> 3) + (lid >> 3);
    const u32 bz = nl >> (lgx + lgy);
    const u32 by = (nl >> lgx) & (gy - 1);
    const u32 bx = nl & (gx - 1);

    const u16* __restrict__ A   = g.A[bz];
    const u16* __restrict__ Wt  = g.Wt[bz];
    const float* __restrict__ bias = g.bias[bz];
    void* __restrict__ Cv = g.C[bz];
    const float scale = g.scale[bz];

    __shared__ u16 sm[2][6144];
    const int tid = threadIdx.x;
    const int w = tid >> 6, lane = tid & 63;
    const int l15 = lane & 15, l4 = lane >> 4;
    const int wr = w & 1, wc = w >> 1;
    const int bm = by << 6, bn = bx << 7;
    const int xq = l4 ^ ((lane >> 1) & 3);

    f32x4 acc[4][2];
    #pragma unroll
    for (int nf = 0; nf < 4; ++nf)
        #pragma unroll
        for (int mf = 0; mf < 2; ++mf){
            acc[nf][mf][0]=0.f; acc[nf][mf][1]=0.f; acc[nf][mf][2]=0.f; acc[nf][mf][3]=0.f;
        }

    auto STAGE = [&](int buf, int kt){
        #pragma unroll
        for (int j = 0; j < 3; ++j){
            int ch = w*192 + j*64 + lane;
            int isB = ch >= 256;
            int cc  = isB ? ch - 256 : ch;
            int row = cc >> 2, q = cc & 3;
            int qs  = q ^ ((row >> 1) & 3);
            const u16* src = isB ? (Wt + (size_t)(bn + row) * K + kt + qs*8)
                                 : (A  + (size_t)(bm + row) * K + kt + qs*8);
#if HAVE_GLL
            u16* lb = &sm[buf][(size_t)(w*192 + j*64) * 8];
            __builtin_amdgcn_global_load_lds((const __attribute__((address_space(1))) void*)src,
                                             (__attribute__((address_space(3))) void*)lb, 16, 0, 0);
#else
            *(i32x4*)&sm[buf][(size_t)ch * 8] = *(const i32x4*)src;
#endif
        }
    };

    STAGE(0, 0);
    const int nk = K >> 5;
    for (int t = 0; t < nk; ++t){
        const int cur = t & 1;
        if (t + 1 < nk){
            STAGE(cur ^ 1, (t + 1) << 5);
#if HAVE_GLL
            asm volatile("s_waitcnt vmcnt(3)" ::: "memory");
#endif
        } else {
#if HAVE_GLL
            asm volatile("s_waitcnt vmcnt(0)" ::: "memory");
#endif
        }
        __builtin_amdgcn_s_barrier();
        asm volatile("" ::: "memory");

        const u16* As = sm[cur];
        const u16* Bs = sm[cur] + 2048;
        bf16x8 wf[4], af[2];
        #pragma unroll
        for (int nf = 0; nf < 4; ++nf)
            wf[nf] = *(const bf16x8*)(Bs + (size_t)(wc*64 + nf*16 + l15) * 32 + xq*8);
        #pragma unroll
        for (int mf = 0; mf < 2; ++mf)
            af[mf] = *(const bf16x8*)(As + (size_t)(wr*32 + mf*16 + l15) * 32 + xq*8);
        __builtin_amdgcn_s_setprio(1);
        #pragma unroll
        for (int nf = 0; nf < 4; ++nf)
            #pragma unroll
            for (int mf = 0; mf < 2; ++mf)
                acc[nf][mf] = __builtin_amdgcn_mfma_f32_16x16x32_bf16(wf[nf], af[mf], acc[nf][mf], 0, 0, 0);
        __builtin_amdgcn_s_setprio(0);

        asm volatile("" ::: "memory");
        __builtin_amdgcn_s_barrier();
    }

    #pragma unroll
    for (int nf = 0; nf < 4; ++nf){
        const int n0 = bn + wc*64 + nf*16 + l4*4;
        float4 b4 = *(const float4*)(bias + n0);
        #pragma unroll
        for (int mf = 0; mf < 2; ++mf){
            const int m = bm + wr*32 + mf*16 + l15;
            float r0 = (acc[nf][mf][0] + b4.x) * scale;
            float r1 = (acc[nf][mf][1] + b4.y) * scale;
            float r2 = (acc[nf][mf][2] + b4.z) * scale;
            float r3 = (acc[nf][mf][3] + b4.w) * scale;
            if (ACT){ r0 = gelu_f(r0); r1 = gelu_f(r1); r2 = gelu_f(r2); r3 = gelu_f(r3); }
            if (OUTF32){
                float4 o; o.x = r0; o.y = r1; o.z = r2; o.w = r3;
                *(float4*)((float*)Cv + (size_t)m * N + n0) = o;
            } else {
                u64 p = (u64)cvtpk(r0, r1) | ((u64)cvtpk(r2, r3) << 32);
                *(u64*)((u16*)Cv + (size_t)m * N + n0) = p;
            }
        }
    }
}

// ---------------------------------------------------------------------------
// GEMM (grouped, FP32 A): reg-staged A (issue-early, cvt_pk + ds_write late),
// B via GLL with counted vmcnt(4). Output bf16. No input-cvt pass needed.
// ---------------------------------------------------------------------------
struct Grp32 {
    const float* A[6];
    const u16* Wt[6];
    const float* bias[6];
    void* C[6];
    float scale[6];
};

__global__ __launch_bounds__(256, 4) void gemm32_k(Grp32 g, int N, int K)
{
    const u32 gx = gridDim.x, gy = gridDim.y;
    const u32 lgx = (u32)__builtin_ctz(gx);
    const u32 lgy = (u32)__builtin_ctz(gy);
    const u32 total = gx * gy * gridDim.z;
    const u32 lid = (blockIdx.z * gy + blockIdx.y) * gx + blockIdx.x;
    const u32 nl = (lid & 7) * (total >> 3) + (lid >> 3);
    const u32 bz = nl >> (lgx + lgy);
    const u32 by = (nl >> lgx) & (gy - 1);
    const u32 bx = nl & (gx - 1);

    const float* __restrict__ A = g.A[bz];
    const u16* __restrict__ Wt  = g.Wt[bz];
    const float* __restrict__ bias = g.bias[bz];
    void* __restrict__ Cv = g.C[bz];
    const float scale = g.scale[bz];

    __shared__ u16 sm[2][6144];           // A [64][32] @0, B [128][32] @2048
    const int tid = threadIdx.x;
    const int w = tid >> 6, lane = tid & 63;
    const int l15 = lane & 15, l4 = lane >> 4;
    const int wr = w & 1, wc = w >> 1;
    const int bm = by << 6, bn = bx << 7;
    const int xq = l4 ^ ((lane >> 1) & 3);

    f32x4 acc[4][2];
    #pragma unroll
    for (int nf = 0; nf < 4; ++nf)
        #pragma unroll
        for (int mf = 0; mf < 2; ++mf){
            acc[nf][mf][0]=0.f; acc[nf][mf][1]=0.f; acc[nf][mf][2]=0.f; acc[nf][mf][3]=0.f;
        }

    const int arow = tid >> 2, aq = tid & 3;
    const int aqs = aq ^ ((arow >> 1) & 3);
    const float* Ab = A + (size_t)(bm + arow) * K + aqs*8;
    float4 a0r, a1r;
    auto A_ISSUE = [&](int kt){
        a0r = *(const float4*)(Ab + kt);
        a1r = *(const float4*)(Ab + kt + 4);
    };
    auto A_WRITE = [&](int buf){
        i32x4 o;
        o[0] = (int)cvtpk(a0r.x, a0r.y); o[1] = (int)cvtpk(a0r.z, a0r.w);
        o[2] = (int)cvtpk(a1r.x, a1r.y); o[3] = (int)cvtpk(a1r.z, a1r.w);
        *(i32x4*)&sm[buf][(size_t)tid * 8] = o;
    };
    auto B_STAGE = [&](int buf, int kt){
        #pragma unroll
        for (int j = 0; j < 2; ++j){
            int ch = w*128 + j*64 + lane;
            int row = ch >> 2, q = ch & 3;
            int qs  = q ^ ((row >> 1) & 3);
            const u16* src = Wt + (size_t)(bn + row) * K + kt + qs*8;
#if HAVE_GLL
            u16* lb = &sm[buf][2048 + (size_t)(w*128 + j*64) * 8];
            __builtin_amdgcn_global_load_lds((const __attribute__((address_space(1))) void*)src,
                                             (__attribute__((address_space(3))) void*)lb, 16, 0, 0);
#else
            *(i32x4*)&sm[buf][2048 + (size_t)ch * 8] = *(const i32x4*)src;
#endif
        }
    };

    A_ISSUE(0);
    B_STAGE(0, 0);
    A_WRITE(0);
    __syncthreads();

    const int nk = K >> 5;
    for (int t = 0; t < nk; ++t){
        const int cur = t & 1;
        if (t + 1 < nk){
            A_ISSUE((t + 1) << 5);
            B_STAGE(cur ^ 1, (t + 1) << 5);
#if HAVE_GLL
            asm volatile("s_waitcnt vmcnt(4)" ::: "memory");
#endif
        } else {
#if HAVE_GLL
            asm volatile("s_waitcnt vmcnt(0)" ::: "memory");
#endif
        }
        __builtin_amdgcn_s_barrier();
        asm volatile("" ::: "memory");

        const u16* As = sm[cur];
        const u16* Bs = sm[cur] + 2048;
        bf16x8 wf[4], af[2];
        #pragma unroll
        for (int nf = 0; nf < 4; ++nf)
            wf[nf] = *(const bf16x8*)(Bs + (size_t)(wc*64 + nf*16 + l15) * 32 + xq*8);
        #pragma unroll
        for (int mf = 0; mf < 2; ++mf)
            af[mf] = *(const bf16x8*)(As + (size_t)(wr*32 + mf*16 + l15) * 32 + xq*8);
        __builtin_amdgcn_s_setprio(1);
        #pragma unroll
        for (int nf = 0; nf < 4; ++nf)
            #pragma unroll
            for (int mf = 0; mf < 2; ++mf)
                acc[nf][mf] = __builtin_amdgcn_mfma_f32_16x16x32_bf16(wf[nf], af[mf], acc[nf][mf], 0, 0, 0);
        __builtin_amdgcn_s_setprio(0);

        if (t + 1 < nk) A_WRITE(cur ^ 1);
        asm volatile("" ::: "memory");
        asm volatile("s_waitcnt lgkmcnt(0)" ::: "memory");
        __builtin_amdgcn_s_barrier();
    }

    #pragma unroll
    for (int nf = 0; nf < 4; ++nf){
        const int n0 = bn + wc*64 + nf*16 + l4*4;
        float4 b4 = *(const float4*)(bias + n0);
        #pragma unroll
        for (int mf = 0; mf < 2; ++mf){
            const int m = bm + wr*32 + mf*16 + l15;
            float r0 = (acc[nf][mf][0] + b4.x) * scale;
            float r1 = (acc[nf][mf][1] + b4.y) * scale;
            float r2 = (acc[nf][mf][2] + b4.z) * scale;
            float r3 = (acc[nf][mf][3] + b4.w) * scale;
            u64 p = (u64)cvtpk(r0, r1) | ((u64)cvtpk(r2, r3) << 32);
            *(u64*)((u16*)Cv + (size_t)m * N + n0) = p;
        }
    }
}

// ---------------------------------------------------------------------------
// bf16 MFMA flash attention — r6 structure (KV tile 64, 4 waves x 32q,
// [64][72]-padded K and V^T double-buffered LDS, one barrier per tile) with
// TWO register sets and 2-TILES-AHEAD prefetch, plus raw s_barrier with
// lgkmcnt(0)-only drain so the prefetch loads stay in flight across barriers
// (T4). Math sequence bit-identical to r6. Fixed m=0 softmax (Q pre-scaled).
// ---------------------------------------------------------------------------
template<int FUSE>
__global__ __launch_bounds__(256, 2) void attn_k(const u16* __restrict__ Q, const u16* __restrict__ Kp,
                                                 const u16* __restrict__ Vp, u16* __restrict__ O,
                                                 const u16* __restrict__ ADD)
{
    __shared__ u16 Kl[2][4608];          // [buf][64*72]
    __shared__ u16 Vt[2][4608];          // [buf][d*72 + k]

    const int tid = threadIdx.x;
    const int w = tid >> 6, lane = tid & 63;
    const int c31 = lane & 31, h = lane >> 5;

    // XCD-chunked swizzle: 512 blocks -> each XCD owns 4 heads x 16 q-blocks
    const int lid = blockIdx.x;
    const int nl = (lid & 7) * 64 + (lid >> 3);
    const int bh = nl >> 4;
    const int qb = (nl & 15) << 7;
    const size_t hb = (size_t)(bh >> 2) * Sn * Dn + (size_t)(bh & 3) * DHn;
    const int qrow = qb + w*32 + c31;

    bf16x8 qf[4];
    #pragma unroll
    for (int kc = 0; kc < 4; ++kc)
        qf[kc] = *(const bf16x8*)(Q + hb + (size_t)qrow * Dn + kc*16 + h*8);

    f32x16 ot0, ot1;
    #pragma unroll
    for (int r = 0; r < 16; ++r){ ot0[r] = 0.f; ot1[r] = 0.f; }
    float ll = 0.f;

    int koff0[4], koff1[4];
    #pragma unroll
    for (int kc = 0; kc < 4; ++kc){
        koff0[kc] = c31*72        + kc*16 + h*8;
        koff1[kc] = (32 + c31)*72 + kc*16 + h*8;
    }

    const int krow = tid >> 2, kq = tid & 3;              // K: 2x16B/thread
    const int vk0 = (tid & 15) * 4, vd0 = (tid >> 4) * 4; // V^T: 4x4 block/thread
    const u32 SEL_LO = 0x05040100u, SEL_HI = 0x07060302u;

    // --- two independent register sets (A: even tiles, B: odd tiles)
    i32x4 krA0, krA1, krB0, krB1;
    u64 vA0, vA1, vA2, vA3, vB0, vB1, vB2, vB3;

    auto LOADA = [&](int kt2){
        const u16* kb = Kp + hb + (size_t)(kt2 + krow) * Dn + kq*8;
        krA0 = *(const i32x4*)kb;
        krA1 = *(const i32x4*)(kb + 32);
        const u16* vb = Vp + hb + (size_t)(kt2 + vk0) * Dn + vd0;
        vA0 = *(const u64*)(vb);
        vA1 = *(const u64*)(vb + Dn);
        vA2 = *(const u64*)(vb + 2*Dn);
        vA3 = *(const u64*)(vb + 3*Dn);
    };
    auto LOADB = [&](int kt2){
        const u16* kb = Kp + hb + (size_t)(kt2 + krow) * Dn + kq*8;
        krB0 = *(const i32x4*)kb;
        krB1 = *(const i32x4*)(kb + 32);
        const u16* vb = Vp + hb + (size_t)(kt2 + vk0) * Dn + vd0;
        vB0 = *(const u64*)(vb);
        vB1 = *(const u64*)(vb + Dn);
        vB2 = *(const u64*)(vb + 2*Dn);
        vB3 = *(const u64*)(vb + 3*Dn);
    };
    auto WRITEA = [&](int buf){
        *(i32x4*)&Kl[buf][(size_t)krow*72 + kq*8]      = krA0;
        *(i32x4*)&Kl[buf][(size_t)krow*72 + kq*8 + 32] = krA1;
        u32 a0 = (u32)vA0, a1 = (u32)vA1, a2 = (u32)vA2, a3 = (u32)vA3;
        u32 b0 = (u32)(vA0 >> 32), b1 = (u32)(vA1 >> 32), b2 = (u32)(vA2 >> 32), b3 = (u32)(vA3 >> 32);
        u64 wd0 = (u64)__builtin_amdgcn_perm(a1, a0, SEL_LO) | ((u64)__builtin_amdgcn_perm(a3, a2, SEL_LO) << 32);
        u64 wd1 = (u64)__builtin_amdgcn_perm(a1, a0, SEL_HI) | ((u64)__builtin_amdgcn_perm(a3, a2, SEL_HI) << 32);
        u64 wd2 = (u64)__builtin_amdgcn_perm(b1, b0, SEL_LO) | ((u64)__builtin_amdgcn_perm(b3, b2, SEL_LO) << 32);
        u64 wd3 = (u64)__builtin_amdgcn_perm(b1, b0, SEL_HI) | ((u64)__builtin_amdgcn_perm(b3, b2, SEL_HI) << 32);
        *(u64*)&Vt[buf][(size_t)(vd0 + 0)*72 + vk0] = wd0;
        *(u64*)&Vt[buf][(size_t)(vd0 + 1)*72 + vk0] = wd1;
        *(u64*)&Vt[buf][(size_t)(vd0 + 2)*72 + vk0] = wd2;
        *(u64*)&Vt[buf][(size_t)(vd0 + 3)*72 + vk0] = wd3;
    };
    auto WRITEB = [&](int buf){
        *(i32x4*)&Kl[buf][(size_t)krow*72 + kq*8]      = krB0;
        *(i32x4*)&Kl[buf][(size_t)krow*72 + kq*8 + 32] = krB1;
        u32 a0 = (u32)vB0, a1 = (u32)vB1, a2 = (u32)vB2, a3 = (u32)vB3;
        u32 b0 = (u32)(vB0 >> 32), b1 = (u32)(vB1 >> 32), b2 = (u32)(vB2 >> 32), b3 = (u32)(vB3 >> 32);
        u64 wd0 = (u64)__builtin_amdgcn_perm(a1, a0, SEL_LO) | ((u64)__builtin_amdgcn_perm(a3, a2, SEL_LO) << 32);
        u64 wd1 = (u64)__builtin_amdgcn_perm(a1, a0, SEL_HI) | ((u64)__builtin_amdgcn_perm(a3, a2, SEL_HI) << 32);
        u64 wd2 = (u64)__builtin_amdgcn_perm(b1, b0, SEL_LO) | ((u64)__builtin_amdgcn_perm(b3, b2, SEL_LO) << 32);
        u64 wd3 = (u64)__builtin_amdgcn_perm(b1, b0, SEL_HI) | ((u64)__builtin_amdgcn_perm(b3, b2, SEL_HI) << 32);
        *(u64*)&Vt[buf][(size_t)(vd0 + 0)*72 + vk0] = wd0;
        *(u64*)&Vt[buf][(size_t)(vd0 + 1)*72 + vk0] = wd1;
        *(u64*)&Vt[buf][(size_t)(vd0 + 2)*72 + vk0] = wd2;
        *(u64*)&Vt[buf][(size_t)(vd0 + 3)*72 + vk0] = wd3;
    };

    auto COMPUTE = [&](int c){
        // --- S^T = K @ Q^T  (per lane: 32 pre-scaled scores for q = c31)
        f32x16 s0, s1;
        #pragma unroll
        for (int r = 0; r < 16; ++r){ s0[r] = 0.f; s1[r] = 0.f; }
        __builtin_amdgcn_s_setprio(1);
        #pragma unroll
        for (int kc = 0; kc < 4; ++kc){
            bf16x8 k0 = *(const bf16x8*)&Kl[c][koff0[kc]];
            bf16x8 k1 = *(const bf16x8*)&Kl[c][koff1[kc]];
            s0 = __builtin_amdgcn_mfma_f32_32x32x16_bf16(k0, qf[kc], s0, 0, 0, 0);
            s1 = __builtin_amdgcn_mfma_f32_32x32x16_bf16(k1, qf[kc], s1, 0, 0, 0);
        }
        __builtin_amdgcn_s_setprio(0);

        // --- softmax numerator, fixed m=0: p = exp2(s); packed-pair sums
        f32x2 pp0[8], pp1[8];
        f32x2 rv = {0.f, 0.f};
        #pragma unroll
        for (int r = 0; r < 8; ++r){
            pp0[r][0] = exp2f(s0[2*r]); pp0[r][1] = exp2f(s0[2*r+1]);
            pp1[r][0] = exp2f(s1[2*r]); pp1[r][1] = exp2f(s1[2*r+1]);
            rv += pp0[r];
            rv += pp1[r];
        }
        ll += rv[0] + rv[1];

        // --- pack P^T fragments (cvt_pk + permlane32_swap) and PV MFMA
        __builtin_amdgcn_s_setprio(1);
        #pragma unroll
        for (int kc = 0; kc < 4; ++kc){
            const int iA = 2*kc, iB = 2*kc + 1;
            u32 wA0, wA1, wB0, wB1;
            if (kc < 2){
                wA0 = cvtpk(pp0[iA*2+0][0], pp0[iA*2+0][1]);
                wA1 = cvtpk(pp0[iA*2+1][0], pp0[iA*2+1][1]);
                wB0 = cvtpk(pp0[iB*2+0][0], pp0[iB*2+0][1]);
                wB1 = cvtpk(pp0[iB*2+1][0], pp0[iB*2+1][1]);
            } else {
                wA0 = cvtpk(pp1[(iA-4)*2+0][0], pp1[(iA-4)*2+0][1]);
                wA1 = cvtpk(pp1[(iA-4)*2+1][0], pp1[(iA-4)*2+1][1]);
                wB0 = cvtpk(pp1[(iB-4)*2+0][0], pp1[(iB-4)*2+0][1]);
                wB1 = cvtpk(pp1[(iB-4)*2+1][0], pp1[(iB-4)*2+1][1]);
            }
            i32x4 pw;
#if HAVE_PLS
            {
                auto r02 = __builtin_amdgcn_permlane32_swap((int)wA0, (int)wB0, false, false);
                auto r13 = __builtin_amdgcn_permlane32_swap((int)wA1, (int)wB1, false, false);
                pw[0] = r02[0]; pw[1] = r13[0]; pw[2] = r02[1]; pw[3] = r13[1];
            }
#else
            {
                u32 s0v = h ? wA0 : wB0, s1v = h ? wA1 : wB1;
                u32 g0 = (u32)__shfl_xor((int)s0v, 32);
                u32 g1 = (u32)__shfl_xor((int)s1v, 32);
                pw[0] = (int)(h ? g0 : wA0);
                pw[1] = (int)(h ? g1 : wA1);
                pw[2] = (int)(h ? wB0 : g0);
                pw[3] = (int)(h ? wB1 : g1);
            }
#endif
            bf16x8 pb = *(bf16x8*)&pw;
            bf16x8 va  = *(const bf16x8*)&Vt[c][koff0[kc]];
            bf16x8 vb2 = *(const bf16x8*)&Vt[c][koff1[kc]];
            ot0 = __builtin_amdgcn_mfma_f32_32x32x16_bf16(va,  pb, ot0, 0, 0, 0);
            ot1 = __builtin_amdgcn_mfma_f32_32x32x16_bf16(vb2, pb, ot1, 0, 0, 0);
        }
        __builtin_amdgcn_s_setprio(0);
    };

    // prologue: tile0 -> buf0 (set A); prefetch tile1 (set B)
    LOADA(0);
    WRITEA(0);
    LOADB(1 << 6);
    asm volatile("s_waitcnt lgkmcnt(0)" ::: "memory");
    __builtin_amdgcn_s_barrier();
    asm volatile("" ::: "memory");

    for (int tp = 0; tp < 16; ++tp){
        // ---- tile 2tp (buf 0): prefetch tile 2tp+2 into set A
        if (tp < 15) LOADA((2*tp + 2) << 6);
        COMPUTE(0);
        WRITEB(1);                       // tile 2tp+1 -> buf1 (waits its own vmcnt, counted)
        asm volatile("s_waitcnt lgkmcnt(0)" ::: "memory");
        __builtin_amdgcn_s_barrier();
        asm volatile("" ::: "memory");

        // ---- tile 2tp+1 (buf 1): prefetch tile 2tp+3 into set B
        if (tp < 15) LOADB((2*tp + 3) << 6);
        COMPUTE(1);
        if (tp < 15) WRITEA(0);          // tile 2tp+2 -> buf0
        asm volatile("s_waitcnt lgkmcnt(0)" ::: "memory");
        __builtin_amdgcn_s_barrier();
        asm volatile("" ::: "memory");
    }

    // --- combine lane-halves, normalize, store (optional fused add)
    ll += __shfl_xor(ll, 32);
    float inv = 1.0f / ll;
    #pragma unroll
    for (int rg = 0; rg < 4; ++rg){
        int d0 = 8*rg + 4*h;
        float r0 = ot0[4*rg+0]*inv, r1 = ot0[4*rg+1]*inv, r2 = ot0[4*rg+2]*inv, r3 = ot0[4*rg+3]*inv;
        float x0 = ot1[4*rg+0]*inv, x1 = ot1[4*rg+1]*inv, x2 = ot1[4*rg+2]*inv, x3 = ot1[4*rg+3]*inv;
        if (FUSE){
            u64 ga = *(const u64*)&ADD[hb + (size_t)qrow * Dn + d0];
            u64 gb = *(const u64*)&ADD[hb + (size_t)qrow * Dn + 32 + d0];
            r0 += b2f((u16)ga);         r1 += b2f((u16)(ga >> 16));
            r2 += b2f((u16)(ga >> 32)); r3 += b2f((u16)(ga >> 48));
            x0 += b2f((u16)gb);         x1 += b2f((u16)(gb >> 16));
            x2 += b2f((u16)(gb >> 32)); x3 += b2f((u16)(gb >> 48));
        }
        *(u64*)&O[hb + (size_t)qrow * Dn + d0]      = (u64)cvtpk(r0, r1) | ((u64)cvtpk(r2, r3) << 32);
        *(u64*)&O[hb + (size_t)qrow * Dn + 32 + d0] = (u64)cvtpk(x0, x1) | ((u64)cvtpk(x2, x3) << 32);
    }
}

// ---------------------------------------------------------------------------
// Orchestration.
//   glb_ctx + plb_ctx = glb_probs @ (gv + plb_probs @ pv)       [attn fold]
//   pq = lf@(Wl1@Wpq)+bc, gq = gf@(Wg@Wgq)+bc, gk/gv = lf@(Wl2@Wg{k,v})+bc
//   projections read fp32 inputs directly (gemm32_k) — no input-cvt pass
// ---------------------------------------------------------------------------
extern "C" void kernel_launch(void* const* d_in, const int* in_sizes, int n_in,
                              void* d_out, int out_size, void* d_ws, size_t ws_size,
                              hipStream_t stream)
{
    (void)in_sizes; (void)n_in; (void)out_size; (void)ws_size;

    const float* gf  = (const float*)d_in[0];
    const float* lf  = (const float*)d_in[1];
    const float* tf  = (const float*)d_in[2];
    const float* Wl1 = (const float*)d_in[3];  const float* bl1 = (const float*)d_in[4];
    const float* Wl2 = (const float*)d_in[5];  const float* bl2 = (const float*)d_in[6];
    const float* Wg  = (const float*)d_in[7];  const float* bg  = (const float*)d_in[8];
    const float* Wgq = (const float*)d_in[9];  const float* bgq = (const float*)d_in[10];
    const float* Wgk = (const float*)d_in[11]; const float* bgk = (const float*)d_in[12];
    const float* Wgv = (const float*)d_in[13]; const float* bgv = (const float*)d_in[14];
    const float* Wpq = (const float*)d_in[15]; const float* bpq = (const float*)d_in[16];
    const float* bpk = (const float*)d_in[18];
    const float* bpv = (const float*)d_in[20];
    const float* bd  = (const float*)d_in[22];
    const float* bm1 = (const float*)d_in[24];
    const float* bm2 = (const float*)d_in[26];
    const float* Wml = (const float*)d_in[27]; const float* bml = (const float*)d_in[28];

    const float C1 = 0.18033688011112042f;     // log2(e)/8, folded into pq/gq

    u16* ws = (u16*)d_ws;
    const size_t U = (size_t)Mn * Dn;          // 4,194,304 elems (8 MiB bf16)
    u16* S[9];
    for (int i = 0; i < 9; ++i) S[i] = ws + (size_t)i * U;
    u16* wtb = ws + 9 * U;

    const int sq = 65536;
    u16* Wpqt = wtb + 0*sq;  u16* Wgqt = wtb + 1*sq;  u16* Wgkt = wtb + 2*sq;  u16* Wgvt = wtb + 3*sq;
    u16* Wpkt = wtb + 4*sq;  u16* Wpvt = wtb + 5*sq;  u16* Wdt  = wtb + 6*sq;  u16* Wmlt = wtb + 7*sq;
    u16* Wm1t  = wtb + 524288;             // [1024][256] (transposed)
    u16* Wm2t  = wtb + 786432;             // [256][1024] (transposed)
    u16* Wl1rm = wtb + 1048576;
    u16* Wl2rm = wtb + 1114112;
    u16* Wgrm  = wtb + 1179648;
    u16* Wcpqt = wtb + 1245184;            // combined (W1@W2)^T bf16, 4x
    u16* Wcgqt = wtb + 1310720;
    u16* Wcgkt = wtb + 1376256;
    u16* Wcgvt = wtb + 1441792;
    float* fb  = (float*)(wtb + 1507328);  // biases: 4x256 @0, zero @1024

    // --- prep: weight cvt + bias-combine, one launch (no input cvt)
    WtArgs wa;
    const float* wsrc[13] = {Wpq, Wgq, Wgk, Wgv, (const float*)d_in[17], (const float*)d_in[19],
                             (const float*)d_in[21], Wml,
                             (const float*)d_in[23], (const float*)d_in[25], Wl1, Wl2, Wg};
    const int wdst[13] = {0, sq, 2*sq, 3*sq, 4*sq, 5*sq, 6*sq, 7*sq, 524288, 786432,
                          1048576, 1114112, 1179648};
    for (int i = 0; i < 13; ++i){
        wa.src[i] = wsrc[i];
        wa.kdim[i] = 256; wa.ndim[i] = 256;
        wa.dstoff[i] = wdst[i];
        wa.rm[i] = (i >= 10);
    }
    wa.ndim[8] = 1024;                 // Wm1 [256][1024] -> T [1024][256]
    wa.kdim[9] = 1024;                 // Wm2 [1024][256] -> T [256][1024]
    int acc_t = 0;
    for (int i = 0; i < 13; ++i){
        wa.t0[i] = acc_t;
        acc_t += (wa.ndim[i] >> 5) * (wa.kdim[i] >> 5);
    }
    BcArgs bc;
    bc.W2[0] = Wpq; bc.W2[1] = Wgq; bc.W2[2] = Wgk; bc.W2[3] = Wgv;
    bc.b1[0] = bl1; bc.b1[1] = bg;  bc.b1[2] = bl2; bc.b1[3] = bl2;
    bc.b2[0] = bpq; bc.b2[1] = bgq; bc.b2[2] = bgk; bc.b2[3] = bgv;
    bc.off[0] = 0; bc.off[1] = 256; bc.off[2] = 512; bc.off[3] = 768;
    bc.fb = fb; bc.bc0 = acc_t;
    prep_k<<<dim3(acc_t + 4), 256, 0, stream>>>(wa, wtb, bc);

    auto GN = [&](const Grp& g, int ng, int M, int N, int K, int act, int of32){
        dim3 gr(N / 128, M / 64, ng);
        if (act)        gemm_k<1,0><<<gr, 256, 0, stream>>>(g, N, K);
        else if (of32)  gemm_k<0,1><<<gr, 256, 0, stream>>>(g, N, K);
        else            gemm_k<0,0><<<gr, 256, 0, stream>>>(g, N, K);
    };
    auto G1 = [&](const u16* A, const u16* Wt_, const float* b, void* C, int M, int N, int K,
                  float sc, int act, int of32){
        Grp g{};
        g.A[0] = A; g.Wt[0] = Wt_; g.bias[0] = b; g.C[0] = C; g.scale[0] = sc;
        GN(g, 1, M, N, K, act, of32);
    };

    // --- mini grouped GEMM: Wc^T = W2^T @ W1^T  (M=256, 32 blocks)
    {
        Grp g{};
        g.A[0] = Wpqt; g.Wt[0] = Wl1rm; g.bias[0] = fb + 1024; g.C[0] = Wcpqt; g.scale[0] = 1.f;
        g.A[1] = Wgqt; g.Wt[1] = Wgrm;  g.bias[1] = fb + 1024; g.C[1] = Wcgqt; g.scale[1] = 1.f;
        g.A[2] = Wgkt; g.Wt[2] = Wl2rm; g.bias[2] = fb + 1024; g.C[2] = Wcgkt; g.scale[2] = 1.f;
        g.A[3] = Wgvt; g.Wt[3] = Wl2rm; g.bias[3] = fb + 1024; g.C[3] = Wcgvt; g.scale[3] = 1.f;
        GN(g, 4, 256, 256, 256, 0, 0);
    }

    // --- all 6 projections in ONE grouped launch, reading fp32 inputs
    {
        Grp32 g{};
        g.A[0] = lf; g.Wt[0] = Wcpqt; g.bias[0] = fb + 0;   g.C[0] = S[3]; g.scale[0] = C1;  // pq~
        g.A[1] = gf; g.Wt[1] = Wcgqt; g.bias[1] = fb + 256; g.C[1] = S[6]; g.scale[1] = C1;  // gq~
        g.A[2] = lf; g.Wt[2] = Wcgkt; g.bias[2] = fb + 512; g.C[2] = S[7]; g.scale[2] = 1.f; // gk
        g.A[3] = lf; g.Wt[3] = Wcgvt; g.bias[3] = fb + 768; g.C[3] = S[8]; g.scale[3] = 1.f; // gv
        g.A[4] = tf; g.Wt[4] = Wpkt;  g.bias[4] = bpk;      g.C[4] = S[4]; g.scale[4] = 1.f; // pk
        g.A[5] = tf; g.Wt[5] = Wpvt;  g.bias[5] = bpv;      g.C[5] = S[5]; g.scale[5] = 1.f; // pv
        dim3 gr(2, Mn / 64, 6);
        gemm32_k<<<gr, 256, 0, stream>>>(g, 256, 256);
    }

    // --- attention: vsum = attn(pq,pk,pv) + gv ; ctx = attn(gq,gk,vsum)
    attn_k<1><<<dim3(512), 256, 0, stream>>>(S[3], S[4], S[5], S[0], S[8]);
    attn_k<0><<<dim3(512), 256, 0, stream>>>(S[6], S[7], S[0], S[1], nullptr);

    // --- output projection + MLP (unfused tail: numerics-safe)
    G1(S[1], Wdt,  bd,  S[2],  Mn, 256,  256,  1.f, 0, 0);  // out1
    G1(S[2], Wm1t, bm1, S[3],  Mn, 1024, 256,  1.f, 1, 0);  // hid = gelu(...), spans S3..S6
    G1(S[3], Wm2t, bm2, S[7],  Mn, 256,  1024, 1.f, 0, 0);  // out2
    G1(S[7], Wmlt, bml, d_out, Mn, 256,  256,  1.f, 0, 1);  // final (fp32 out)
}

// Round 13
// 217.709 us; speedup vs baseline: 1.3668x; 1.0027x over previous
//
#include <hip/hip_runtime.h>
#include <math.h>

#define Bn 8
#define Sn 2048
#define Dn 256
#define Hn 4
#define DHn 64
#define Mn (Bn*Sn)   // 16384 rows

typedef short bf16x8 __attribute__((ext_vector_type(8)));
typedef float f32x2  __attribute__((ext_vector_type(2)));
typedef float f32x4  __attribute__((ext_vector_type(4)));
typedef float f32x16 __attribute__((ext_vector_type(16)));
typedef int   i32x4  __attribute__((ext_vector_type(4)));
typedef unsigned short u16;
typedef unsigned int   u32;
typedef unsigned long long u64;

#if defined(__has_builtin)
#if __has_builtin(__builtin_amdgcn_global_load_lds)
#define HAVE_GLL 1
#endif
#if __has_builtin(__builtin_amdgcn_permlane32_swap)
#define HAVE_PLS 1
#endif
#endif
#ifndef HAVE_GLL
#define HAVE_GLL 0
#endif
#ifndef HAVE_PLS
#define HAVE_PLS 0
#endif

// ---------------------------------------------------------------------------
// helpers
// ---------------------------------------------------------------------------
__device__ __forceinline__ u16 f2b(float f){
    u32 u = __float_as_uint(f);
    u32 r = (u + 0x7fffu + ((u >> 16) & 1u)) >> 16;
    return (u16)r;
}
__device__ __forceinline__ float b2f(u16 h){ return __uint_as_float(((u32)h) << 16); }
__device__ __forceinline__ u32 cvtpk(float lo, float hi){
    u32 r;
    asm("v_cvt_pk_bf16_f32 %0, %1, %2" : "=v"(r) : "v"(lo), "v"(hi));
    return r;
}

// gelu(x) = x - x / (exp2(K1*x + K2*x^3) + 1)   [tanh form, exp2 domain]
__device__ __forceinline__ float gelu_f(float x){
    const float K1 = 2.3021143113f;      // 2*log2(e)*sqrt(2/pi)
    const float K2 = 0.1029390163f;      // K1 * 0.044715
    float x2 = x * x;
    float arg = fmaf(x2 * x, K2, x * K1);
    float e = exp2f(arg);
    float r = __builtin_amdgcn_rcpf(e + 1.0f);
    return x - x * r;
}

// ---------------------------------------------------------------------------
// XCD-aware block remap for GEMM reuse topology: each XCD owns a CONTIGUOUS
// by-range (A-panel chunk); within it, bx innermost (B panels L2-resident),
// then bz (grouped members share A rows via L2). Bijective when gy%8==0;
// identity fallback otherwise. [r12 lesson: the attn-style interleave put
// same-A-panel blocks on different XCDs -> A fetched gx times from HBM.]
// ---------------------------------------------------------------------------
__device__ __forceinline__ void xcd_map(u32& bx, u32& by, u32& bz){
    const u32 gx = gridDim.x, gy = gridDim.y, gz = gridDim.z;
    if ((gy & 7) == 0){
        const u32 lid = (blockIdx.z * gy + blockIdx.y) * gx + blockIdx.x;
        const u32 xcd = lid & 7;
        u32 c = lid >> 3;
        bx = c % gx;  c /= gx;
        bz = c % gz;  c /= gz;
        by = xcd * (gy >> 3) + c;
    } else {
        bx = blockIdx.x; by = blockIdx.y; bz = blockIdx.z;
    }
}

// ---------------------------------------------------------------------------
// prep: weight cvt (transpose or row-major) + bias-combine (last 4 blocks).
// ---------------------------------------------------------------------------
struct WtArgs {
    const float* src[13];
    int kdim[13], ndim[13], dstoff[13], t0[13], rm[13];
};
struct BcArgs {
    const float* W2[4];
    const float* b1[4];
    const float* b2[4];
    int off[4];
    float* fb;
    int bc0;
};

__global__ __launch_bounds__(256) void prep_k(WtArgs a, u16* __restrict__ dst, BcArgs bc)
{
    __shared__ float tile[32][33];
    int bx = blockIdx.x;
    if (bx >= bc.bc0){
        int p = bx - bc.bc0, aa = threadIdx.x;
        const float* W2 = bc.W2[p];
        const float* b1 = bc.b1[p];
        const float* b2 = bc.b2[p];
        float s = b2[aa];
        for (int j = 0; j < 256; ++j) s = fmaf(b1[j], W2[(size_t)j*256 + aa], s);
        bc.fb[bc.off[p] + aa] = s;
        if (p == 0) bc.fb[1024 + aa] = 0.f;
        return;
    }
    int tb = bx;
    int wi = 0;
    #pragma unroll
    for (int i = 1; i < 13; ++i) if (tb >= a.t0[i]) wi = i;
    int tt = tb - a.t0[wi];
    int N = a.ndim[wi], K = a.kdim[wi];
    int ntn = N >> 5;
    int tn = tt % ntn, tk = tt / ntn;
    int n0 = tn * 32, k0 = tk * 32;
    const float* src = a.src[wi];
    u16* out = dst + a.dstoff[wi];
    int r = threadIdx.x >> 5, c = threadIdx.x & 31;
    if (a.rm[wi]){
        #pragma unroll
        for (int rr = 0; rr < 4; ++rr){
            size_t idx = (size_t)(k0 + r*4 + rr) * N + n0 + c;
            out[idx] = f2b(src[idx]);
        }
        return;
    }
    #pragma unroll
    for (int rr = 0; rr < 4; ++rr)
        tile[r*4+rr][c] = src[(size_t)(k0 + r*4 + rr) * N + n0 + c];
    __syncthreads();
    #pragma unroll
    for (int rr = 0; rr < 4; ++rr)
        out[(size_t)(n0 + r*4 + rr) * K + k0 + c] = f2b(tile[c][r*4+rr]);
}

// ---------------------------------------------------------------------------
// GEMM (grouped, bf16 A): C = act((A @ W + bias) * scale). Wt bf16 [N,K].
// 64x128 tile, BK=32, 4 waves, 2-phase dbuf LDS, counted vmcnt(3), GLL w16.
// ---------------------------------------------------------------------------
struct Grp {
    const u16* A[6];
    const u16* Wt[6];
    const float* bias[6];
    void* C[6];
    float scale[6];
};

template<int ACT, int OUTF32>
__global__ __launch_bounds__(256, 4) void gemm_k(Grp g, int N, int K)
{
    u32 bx, by, bz;
    xcd_map(bx, by, bz);

    const u16* __restrict__ A   = g.A[bz];
    const u16* __restrict__ Wt  = g.Wt[bz];
    const float* __restrict__ bias = g.bias[bz];
    void* __restrict__ Cv = g.C[bz];
    const float scale = g.scale[bz];

    __shared__ u16 sm[2][6144];
    const int tid = threadIdx.x;
    const int w = tid >> 6, lane = tid & 63;
    const int l15 = lane & 15, l4 = lane >> 4;
    const int wr = w & 1, wc = w >> 1;
    const int bm = by << 6, bn = bx << 7;
    const int xq = l4 ^ ((lane >> 1) & 3);

    f32x4 acc[4][2];
    #pragma unroll
    for (int nf = 0; nf < 4; ++nf)
        #pragma unroll
        for (int mf = 0; mf < 2; ++mf){
            acc[nf][mf][0]=0.f; acc[nf][mf][1]=0.f; acc[nf][mf][2]=0.f; acc[nf][mf][3]=0.f;
        }

    auto STAGE = [&](int buf, int kt){
        #pragma unroll
        for (int j = 0; j < 3; ++j){
            int ch = w*192 + j*64 + lane;
            int isB = ch >= 256;
            int cc  = isB ? ch - 256 : ch;
            int row = cc >> 2, q = cc & 3;
            int qs  = q ^ ((row >> 1) & 3);
            const u16* src = isB ? (Wt + (size_t)(bn + row) * K + kt + qs*8)
                                 : (A  + (size_t)(bm + row) * K + kt + qs*8);
#if HAVE_GLL
            u16* lb = &sm[buf][(size_t)(w*192 + j*64) * 8];
            __builtin_amdgcn_global_load_lds((const __attribute__((address_space(1))) void*)src,
                                             (__attribute__((address_space(3))) void*)lb, 16, 0, 0);
#else
            *(i32x4*)&sm[buf][(size_t)ch * 8] = *(const i32x4*)src;
#endif
        }
    };

    STAGE(0, 0);
    const int nk = K >> 5;
    for (int t = 0; t < nk; ++t){
        const int cur = t & 1;
        if (t + 1 < nk){
            STAGE(cur ^ 1, (t + 1) << 5);
#if HAVE_GLL
            asm volatile("s_waitcnt vmcnt(3)" ::: "memory");
#endif
        } else {
#if HAVE_GLL
            asm volatile("s_waitcnt vmcnt(0)" ::: "memory");
#endif
        }
        __builtin_amdgcn_s_barrier();
        asm volatile("" ::: "memory");

        const u16* As = sm[cur];
        const u16* Bs = sm[cur] + 2048;
        bf16x8 wf[4], af[2];
        #pragma unroll
        for (int nf = 0; nf < 4; ++nf)
            wf[nf] = *(const bf16x8*)(Bs + (size_t)(wc*64 + nf*16 + l15) * 32 + xq*8);
        #pragma unroll
        for (int mf = 0; mf < 2; ++mf)
            af[mf] = *(const bf16x8*)(As + (size_t)(wr*32 + mf*16 + l15) * 32 + xq*8);
        __builtin_amdgcn_s_setprio(1);
        #pragma unroll
        for (int nf = 0; nf < 4; ++nf)
            #pragma unroll
            for (int mf = 0; mf < 2; ++mf)
                acc[nf][mf] = __builtin_amdgcn_mfma_f32_16x16x32_bf16(wf[nf], af[mf], acc[nf][mf], 0, 0, 0);
        __builtin_amdgcn_s_setprio(0);

        asm volatile("" ::: "memory");
        __builtin_amdgcn_s_barrier();
    }

    #pragma unroll
    for (int nf = 0; nf < 4; ++nf){
        const int n0 = bn + wc*64 + nf*16 + l4*4;
        float4 b4 = *(const float4*)(bias + n0);
        #pragma unroll
        for (int mf = 0; mf < 2; ++mf){
            const int m = bm + wr*32 + mf*16 + l15;
            float r0 = (acc[nf][mf][0] + b4.x) * scale;
            float r1 = (acc[nf][mf][1] + b4.y) * scale;
            float r2 = (acc[nf][mf][2] + b4.z) * scale;
            float r3 = (acc[nf][mf][3] + b4.w) * scale;
            if (ACT){ r0 = gelu_f(r0); r1 = gelu_f(r1); r2 = gelu_f(r2); r3 = gelu_f(r3); }
            if (OUTF32){
                float4 o; o.x = r0; o.y = r1; o.z = r2; o.w = r3;
                *(float4*)((float*)Cv + (size_t)m * N + n0) = o;
            } else {
                u64 p = (u64)cvtpk(r0, r1) | ((u64)cvtpk(r2, r3) << 32);
                *(u64*)((u16*)Cv + (size_t)m * N + n0) = p;
            }
        }
    }
}

// ---------------------------------------------------------------------------
// GEMM (grouped, FP32 A): reg-staged A (issue-early, cvt_pk + ds_write late),
// B via GLL with counted vmcnt(4). Output bf16. No input-cvt pass needed.
// ---------------------------------------------------------------------------
struct Grp32 {
    const float* A[6];
    const u16* Wt[6];
    const float* bias[6];
    void* C[6];
    float scale[6];
};

__global__ __launch_bounds__(256, 4) void gemm32_k(Grp32 g, int N, int K)
{
    u32 bx, by, bz;
    xcd_map(bx, by, bz);

    const float* __restrict__ A = g.A[bz];
    const u16* __restrict__ Wt  = g.Wt[bz];
    const float* __restrict__ bias = g.bias[bz];
    void* __restrict__ Cv = g.C[bz];
    const float scale = g.scale[bz];

    __shared__ u16 sm[2][6144];           // A [64][32] @0, B [128][32] @2048
    const int tid = threadIdx.x;
    const int w = tid >> 6, lane = tid & 63;
    const int l15 = lane & 15, l4 = lane >> 4;
    const int wr = w & 1, wc = w >> 1;
    const int bm = by << 6, bn = bx << 7;
    const int xq = l4 ^ ((lane >> 1) & 3);

    f32x4 acc[4][2];
    #pragma unroll
    for (int nf = 0; nf < 4; ++nf)
        #pragma unroll
        for (int mf = 0; mf < 2; ++mf){
            acc[nf][mf][0]=0.f; acc[nf][mf][1]=0.f; acc[nf][mf][2]=0.f; acc[nf][mf][3]=0.f;
        }

    const int arow = tid >> 2, aq = tid & 3;
    const int aqs = aq ^ ((arow >> 1) & 3);
    const float* Ab = A + (size_t)(bm + arow) * K + aqs*8;
    float4 a0r, a1r;
    auto A_ISSUE = [&](int kt){
        a0r = *(const float4*)(Ab + kt);
        a1r = *(const float4*)(Ab + kt + 4);
    };
    auto A_WRITE = [&](int buf){
        i32x4 o;
        o[0] = (int)cvtpk(a0r.x, a0r.y); o[1] = (int)cvtpk(a0r.z, a0r.w);
        o[2] = (int)cvtpk(a1r.x, a1r.y); o[3] = (int)cvtpk(a1r.z, a1r.w);
        *(i32x4*)&sm[buf][(size_t)tid * 8] = o;
    };
    auto B_STAGE = [&](int buf, int kt){
        #pragma unroll
        for (int j = 0; j < 2; ++j){
            int ch = w*128 + j*64 + lane;
            int row = ch >> 2, q = ch & 3;
            int qs  = q ^ ((row >> 1) & 3);
            const u16* src = Wt + (size_t)(bn + row) * K + kt + qs*8;
#if HAVE_GLL
            u16* lb = &sm[buf][2048 + (size_t)(w*128 + j*64) * 8];
            __builtin_amdgcn_global_load_lds((const __attribute__((address_space(1))) void*)src,
                                             (__attribute__((address_space(3))) void*)lb, 16, 0, 0);
#else
            *(i32x4*)&sm[buf][2048 + (size_t)ch * 8] = *(const i32x4*)src;
#endif
        }
    };

    A_ISSUE(0);
    B_STAGE(0, 0);
    A_WRITE(0);
    __syncthreads();

    const int nk = K >> 5;
    for (int t = 0; t < nk; ++t){
        const int cur = t & 1;
        if (t + 1 < nk){
            A_ISSUE((t + 1) << 5);
            B_STAGE(cur ^ 1, (t + 1) << 5);
#if HAVE_GLL
            asm volatile("s_waitcnt vmcnt(4)" ::: "memory");
#endif
        } else {
#if HAVE_GLL
            asm volatile("s_waitcnt vmcnt(0)" ::: "memory");
#endif
        }
        __builtin_amdgcn_s_barrier();
        asm volatile("" ::: "memory");

        const u16* As = sm[cur];
        const u16* Bs = sm[cur] + 2048;
        bf16x8 wf[4], af[2];
        #pragma unroll
        for (int nf = 0; nf < 4; ++nf)
            wf[nf] = *(const bf16x8*)(Bs + (size_t)(wc*64 + nf*16 + l15) * 32 + xq*8);
        #pragma unroll
        for (int mf = 0; mf < 2; ++mf)
            af[mf] = *(const bf16x8*)(As + (size_t)(wr*32 + mf*16 + l15) * 32 + xq*8);
        __builtin_amdgcn_s_setprio(1);
        #pragma unroll
        for (int nf = 0; nf < 4; ++nf)
            #pragma unroll
            for (int mf = 0; mf < 2; ++mf)
                acc[nf][mf] = __builtin_amdgcn_mfma_f32_16x16x32_bf16(wf[nf], af[mf], acc[nf][mf], 0, 0, 0);
        __builtin_amdgcn_s_setprio(0);

        if (t + 1 < nk) A_WRITE(cur ^ 1);
        asm volatile("" ::: "memory");
        asm volatile("s_waitcnt lgkmcnt(0)" ::: "memory");
        __builtin_amdgcn_s_barrier();
    }

    #pragma unroll
    for (int nf = 0; nf < 4; ++nf){
        const int n0 = bn + wc*64 + nf*16 + l4*4;
        float4 b4 = *(const float4*)(bias + n0);
        #pragma unroll
        for (int mf = 0; mf < 2; ++mf){
            const int m = bm + wr*32 + mf*16 + l15;
            float r0 = (acc[nf][mf][0] + b4.x) * scale;
            float r1 = (acc[nf][mf][1] + b4.y) * scale;
            float r2 = (acc[nf][mf][2] + b4.z) * scale;
            float r3 = (acc[nf][mf][3] + b4.w) * scale;
            u64 p = (u64)cvtpk(r0, r1) | ((u64)cvtpk(r2, r3) << 32);
            *(u64*)((u16*)Cv + (size_t)m * N + n0) = p;
        }
    }
}

// ---------------------------------------------------------------------------
// bf16 MFMA flash attention — r12 structure (converged plateau): KV tile 64,
// 4 waves x 32q, [64][72]-padded K/V^T double-buffered LDS, two register sets
// with 2-tiles-ahead prefetch, raw s_barrier + lgkmcnt(0)-only drain.
// Fixed m=0 softmax (Q pre-scaled by log2e/8 in producer GEMM).
// ---------------------------------------------------------------------------
template<int FUSE>
__global__ __launch_bounds__(256, 2) void attn_k(const u16* __restrict__ Q, const u16* __restrict__ Kp,
                                                 const u16* __restrict__ Vp, u16* __restrict__ O,
                                                 const u16* __restrict__ ADD)
{
    __shared__ u16 Kl[2][4608];          // [buf][64*72]
    __shared__ u16 Vt[2][4608];          // [buf][d*72 + k]

    const int tid = threadIdx.x;
    const int w = tid >> 6, lane = tid & 63;
    const int c31 = lane & 31, h = lane >> 5;

    // XCD-chunked swizzle: 512 blocks -> each XCD owns 4 heads x 16 q-blocks
    const int lid = blockIdx.x;
    const int nl = (lid & 7) * 64 + (lid >> 3);
    const int bh = nl >> 4;
    const int qb = (nl & 15) << 7;
    const size_t hb = (size_t)(bh >> 2) * Sn * Dn + (size_t)(bh & 3) * DHn;
    const int qrow = qb + w*32 + c31;

    bf16x8 qf[4];
    #pragma unroll
    for (int kc = 0; kc < 4; ++kc)
        qf[kc] = *(const bf16x8*)(Q + hb + (size_t)qrow * Dn + kc*16 + h*8);

    f32x16 ot0, ot1;
    #pragma unroll
    for (int r = 0; r < 16; ++r){ ot0[r] = 0.f; ot1[r] = 0.f; }
    float ll = 0.f;

    int koff0[4], koff1[4];
    #pragma unroll
    for (int kc = 0; kc < 4; ++kc){
        koff0[kc] = c31*72        + kc*16 + h*8;
        koff1[kc] = (32 + c31)*72 + kc*16 + h*8;
    }

    const int krow = tid >> 2, kq = tid & 3;              // K: 2x16B/thread
    const int vk0 = (tid & 15) * 4, vd0 = (tid >> 4) * 4; // V^T: 4x4 block/thread
    const u32 SEL_LO = 0x05040100u, SEL_HI = 0x07060302u;

    // --- two independent register sets (A: even tiles, B: odd tiles)
    i32x4 krA0, krA1, krB0, krB1;
    u64 vA0, vA1, vA2, vA3, vB0, vB1, vB2, vB3;

    auto LOADA = [&](int kt2){
        const u16* kb = Kp + hb + (size_t)(kt2 + krow) * Dn + kq*8;
        krA0 = *(const i32x4*)kb;
        krA1 = *(const i32x4*)(kb + 32);
        const u16* vb = Vp + hb + (size_t)(kt2 + vk0) * Dn + vd0;
        vA0 = *(const u64*)(vb);
        vA1 = *(const u64*)(vb + Dn);
        vA2 = *(const u64*)(vb + 2*Dn);
        vA3 = *(const u64*)(vb + 3*Dn);
    };
    auto LOADB = [&](int kt2){
        const u16* kb = Kp + hb + (size_t)(kt2 + krow) * Dn + kq*8;
        krB0 = *(const i32x4*)kb;
        krB1 = *(const i32x4*)(kb + 32);
        const u16* vb = Vp + hb + (size_t)(kt2 + vk0) * Dn + vd0;
        vB0 = *(const u64*)(vb);
        vB1 = *(const u64*)(vb + Dn);
        vB2 = *(const u64*)(vb + 2*Dn);
        vB3 = *(const u64*)(vb + 3*Dn);
    };
    auto WRITEA = [&](int buf){
        *(i32x4*)&Kl[buf][(size_t)krow*72 + kq*8]      = krA0;
        *(i32x4*)&Kl[buf][(size_t)krow*72 + kq*8 + 32] = krA1;
        u32 a0 = (u32)vA0, a1 = (u32)vA1, a2 = (u32)vA2, a3 = (u32)vA3;
        u32 b0 = (u32)(vA0 >> 32), b1 = (u32)(vA1 >> 32), b2 = (u32)(vA2 >> 32), b3 = (u32)(vA3 >> 32);
        u64 wd0 = (u64)__builtin_amdgcn_perm(a1, a0, SEL_LO) | ((u64)__builtin_amdgcn_perm(a3, a2, SEL_LO) << 32);
        u64 wd1 = (u64)__builtin_amdgcn_perm(a1, a0, SEL_HI) | ((u64)__builtin_amdgcn_perm(a3, a2, SEL_HI) << 32);
        u64 wd2 = (u64)__builtin_amdgcn_perm(b1, b0, SEL_LO) | ((u64)__builtin_amdgcn_perm(b3, b2, SEL_LO) << 32);
        u64 wd3 = (u64)__builtin_amdgcn_perm(b1, b0, SEL_HI) | ((u64)__builtin_amdgcn_perm(b3, b2, SEL_HI) << 32);
        *(u64*)&Vt[buf][(size_t)(vd0 + 0)*72 + vk0] = wd0;
        *(u64*)&Vt[buf][(size_t)(vd0 + 1)*72 + vk0] = wd1;
        *(u64*)&Vt[buf][(size_t)(vd0 + 2)*72 + vk0] = wd2;
        *(u64*)&Vt[buf][(size_t)(vd0 + 3)*72 + vk0] = wd3;
    };
    auto WRITEB = [&](int buf){
        *(i32x4*)&Kl[buf][(size_t)krow*72 + kq*8]      = krB0;
        *(i32x4*)&Kl[buf][(size_t)krow*72 + kq*8 + 32] = krB1;
        u32 a0 = (u32)vB0, a1 = (u32)vB1, a2 = (u32)vB2, a3 = (u32)vB3;
        u32 b0 = (u32)(vB0 >> 32), b1 = (u32)(vB1 >> 32), b2 = (u32)(vB2 >> 32), b3 = (u32)(vB3 >> 32);
        u64 wd0 = (u64)__builtin_amdgcn_perm(a1, a0, SEL_LO) | ((u64)__builtin_amdgcn_perm(a3, a2, SEL_LO) << 32);
        u64 wd1 = (u64)__builtin_amdgcn_perm(a1, a0, SEL_HI) | ((u64)__builtin_amdgcn_perm(a3, a2, SEL_HI) << 32);
        u64 wd2 = (u64)__builtin_amdgcn_perm(b1, b0, SEL_LO) | ((u64)__builtin_amdgcn_perm(b3, b2, SEL_LO) << 32);
        u64 wd3 = (u64)__builtin_amdgcn_perm(b1, b0, SEL_HI) | ((u64)__builtin_amdgcn_perm(b3, b2, SEL_HI) << 32);
        *(u64*)&Vt[buf][(size_t)(vd0 + 0)*72 + vk0] = wd0;
        *(u64*)&Vt[buf][(size_t)(vd0 + 1)*72 + vk0] = wd1;
        *(u64*)&Vt[buf][(size_t)(vd0 + 2)*72 + vk0] = wd2;
        *(u64*)&Vt[buf][(size_t)(vd0 + 3)*72 + vk0] = wd3;
    };

    auto COMPUTE = [&](int c){
        f32x16 s0, s1;
        #pragma unroll
        for (int r = 0; r < 16; ++r){ s0[r] = 0.f; s1[r] = 0.f; }
        __builtin_amdgcn_s_setprio(1);
        #pragma unroll
        for (int kc = 0; kc < 4; ++kc){
            bf16x8 k0 = *(const bf16x8*)&Kl[c][koff0[kc]];
            bf16x8 k1 = *(const bf16x8*)&Kl[c][koff1[kc]];
            s0 = __builtin_amdgcn_mfma_f32_32x32x16_bf16(k0, qf[kc], s0, 0, 0, 0);
            s1 = __builtin_amdgcn_mfma_f32_32x32x16_bf16(k1, qf[kc], s1, 0, 0, 0);
        }
        __builtin_amdgcn_s_setprio(0);

        f32x2 pp0[8], pp1[8];
        f32x2 rv = {0.f, 0.f};
        #pragma unroll
        for (int r = 0; r < 8; ++r){
            pp0[r][0] = exp2f(s0[2*r]); pp0[r][1] = exp2f(s0[2*r+1]);
            pp1[r][0] = exp2f(s1[2*r]); pp1[r][1] = exp2f(s1[2*r+1]);
            rv += pp0[r];
            rv += pp1[r];
        }
        ll += rv[0] + rv[1];

        __builtin_amdgcn_s_setprio(1);
        #pragma unroll
        for (int kc = 0; kc < 4; ++kc){
            const int iA = 2*kc, iB = 2*kc + 1;
            u32 wA0, wA1, wB0, wB1;
            if (kc < 2){
                wA0 = cvtpk(pp0[iA*2+0][0], pp0[iA*2+0][1]);
                wA1 = cvtpk(pp0[iA*2+1][0], pp0[iA*2+1][1]);
                wB0 = cvtpk(pp0[iB*2+0][0], pp0[iB*2+0][1]);
                wB1 = cvtpk(pp0[iB*2+1][0], pp0[iB*2+1][1]);
            } else {
                wA0 = cvtpk(pp1[(iA-4)*2+0][0], pp1[(iA-4)*2+0][1]);
                wA1 = cvtpk(pp1[(iA-4)*2+1][0], pp1[(iA-4)*2+1][1]);
                wB0 = cvtpk(pp1[(iB-4)*2+0][0], pp1[(iB-4)*2+0][1]);
                wB1 = cvtpk(pp1[(iB-4)*2+1][0], pp1[(iB-4)*2+1][1]);
            }
            i32x4 pw;
#if HAVE_PLS
            {
                auto r02 = __builtin_amdgcn_permlane32_swap((int)wA0, (int)wB0, false, false);
                auto r13 = __builtin_amdgcn_permlane32_swap((int)wA1, (int)wB1, false, false);
                pw[0] = r02[0]; pw[1] = r13[0]; pw[2] = r02[1]; pw[3] = r13[1];
            }
#else
            {
                u32 s0v = h ? wA0 : wB0, s1v = h ? wA1 : wB1;
                u32 g0 = (u32)__shfl_xor((int)s0v, 32);
                u32 g1 = (u32)__shfl_xor((int)s1v, 32);
                pw[0] = (int)(h ? g0 : wA0);
                pw[1] = (int)(h ? g1 : wA1);
                pw[2] = (int)(h ? wB0 : g0);
                pw[3] = (int)(h ? wB1 : g1);
            }
#endif
            bf16x8 pb = *(bf16x8*)&pw;
            bf16x8 va  = *(const bf16x8*)&Vt[c][koff0[kc]];
            bf16x8 vb2 = *(const bf16x8*)&Vt[c][koff1[kc]];
            ot0 = __builtin_amdgcn_mfma_f32_32x32x16_bf16(va,  pb, ot0, 0, 0, 0);
            ot1 = __builtin_amdgcn_mfma_f32_32x32x16_bf16(vb2, pb, ot1, 0, 0, 0);
        }
        __builtin_amdgcn_s_setprio(0);
    };

    // prologue: tile0 -> buf0 (set A); prefetch tile1 (set B)
    LOADA(0);
    WRITEA(0);
    LOADB(1 << 6);
    asm volatile("s_waitcnt lgkmcnt(0)" ::: "memory");
    __builtin_amdgcn_s_barrier();
    asm volatile("" ::: "memory");

    for (int tp = 0; tp < 16; ++tp){
        // ---- tile 2tp (buf 0): prefetch tile 2tp+2 into set A
        if (tp < 15) LOADA((2*tp + 2) << 6);
        COMPUTE(0);
        WRITEB(1);
        asm volatile("s_waitcnt lgkmcnt(0)" ::: "memory");
        __builtin_amdgcn_s_barrier();
        asm volatile("" ::: "memory");

        // ---- tile 2tp+1 (buf 1): prefetch tile 2tp+3 into set B
        if (tp < 15) LOADB((2*tp + 3) << 6);
        COMPUTE(1);
        if (tp < 15) WRITEA(0);
        asm volatile("s_waitcnt lgkmcnt(0)" ::: "memory");
        __builtin_amdgcn_s_barrier();
        asm volatile("" ::: "memory");
    }

    // --- combine lane-halves, normalize, store (optional fused add)
    ll += __shfl_xor(ll, 32);
    float inv = 1.0f / ll;
    #pragma unroll
    for (int rg = 0; rg < 4; ++rg){
        int d0 = 8*rg + 4*h;
        float r0 = ot0[4*rg+0]*inv, r1 = ot0[4*rg+1]*inv, r2 = ot0[4*rg+2]*inv, r3 = ot0[4*rg+3]*inv;
        float x0 = ot1[4*rg+0]*inv, x1 = ot1[4*rg+1]*inv, x2 = ot1[4*rg+2]*inv, x3 = ot1[4*rg+3]*inv;
        if (FUSE){
            u64 ga = *(const u64*)&ADD[hb + (size_t)qrow * Dn + d0];
            u64 gb = *(const u64*)&ADD[hb + (size_t)qrow * Dn + 32 + d0];
            r0 += b2f((u16)ga);         r1 += b2f((u16)(ga >> 16));
            r2 += b2f((u16)(ga >> 32)); r3 += b2f((u16)(ga >> 48));
            x0 += b2f((u16)gb);         x1 += b2f((u16)(gb >> 16));
            x2 += b2f((u16)(gb >> 32)); x3 += b2f((u16)(gb >> 48));
        }
        *(u64*)&O[hb + (size_t)qrow * Dn + d0]      = (u64)cvtpk(r0, r1) | ((u64)cvtpk(r2, r3) << 32);
        *(u64*)&O[hb + (size_t)qrow * Dn + 32 + d0] = (u64)cvtpk(x0, x1) | ((u64)cvtpk(x2, x3) << 32);
    }
}

// ---------------------------------------------------------------------------
// Orchestration.
//   glb_ctx + plb_ctx = glb_probs @ (gv + plb_probs @ pv)       [attn fold]
//   pq = lf@(Wl1@Wpq)+bc, gq = gf@(Wg@Wgq)+bc, gk/gv = lf@(Wl2@Wg{k,v})+bc
//   projections read fp32 inputs directly (gemm32_k) — no input-cvt pass
// ---------------------------------------------------------------------------
extern "C" void kernel_launch(void* const* d_in, const int* in_sizes, int n_in,
                              void* d_out, int out_size, void* d_ws, size_t ws_size,
                              hipStream_t stream)
{
    (void)in_sizes; (void)n_in; (void)out_size; (void)ws_size;

    const float* gf  = (const float*)d_in[0];
    const float* lf  = (const float*)d_in[1];
    const float* tf  = (const float*)d_in[2];
    const float* Wl1 = (const float*)d_in[3];  const float* bl1 = (const float*)d_in[4];
    const float* Wl2 = (const float*)d_in[5];  const float* bl2 = (const float*)d_in[6];
    const float* Wg  = (const float*)d_in[7];  const float* bg  = (const float*)d_in[8];
    const float* Wgq = (const float*)d_in[9];  const float* bgq = (const float*)d_in[10];
    const float* Wgk = (const float*)d_in[11]; const float* bgk = (const float*)d_in[12];
    const float* Wgv = (const float*)d_in[13]; const float* bgv = (const float*)d_in[14];
    const float* Wpq = (const float*)d_in[15]; const float* bpq = (const float*)d_in[16];
    const float* bpk = (const float*)d_in[18];
    const float* bpv = (const float*)d_in[20];
    const float* bd  = (const float*)d_in[22];
    const float* bm1 = (const float*)d_in[24];
    const float* bm2 = (const float*)d_in[26];
    const float* Wml = (const float*)d_in[27]; const float* bml = (const float*)d_in[28];

    const float C1 = 0.18033688011112042f;     // log2(e)/8, folded into pq/gq

    u16* ws = (u16*)d_ws;
    const size_t U = (size_t)Mn * Dn;          // 4,194,304 elems (8 MiB bf16)
    u16* S[9];
    for (int i = 0; i < 9; ++i) S[i] = ws + (size_t)i * U;
    u16* wtb = ws + 9 * U;

    const int sq = 65536;
    u16* Wpqt = wtb + 0*sq;  u16* Wgqt = wtb + 1*sq;  u16* Wgkt = wtb + 2*sq;  u16* Wgvt = wtb + 3*sq;
    u16* Wpkt = wtb + 4*sq;  u16* Wpvt = wtb + 5*sq;  u16* Wdt  = wtb + 6*sq;  u16* Wmlt = wtb + 7*sq;
    u16* Wm1t  = wtb + 524288;             // [1024][256] (transposed)
    u16* Wm2t  = wtb + 786432;             // [256][1024] (transposed)
    u16* Wl1rm = wtb + 1048576;
    u16* Wl2rm = wtb + 1114112;
    u16* Wgrm  = wtb + 1179648;
    u16* Wcpqt = wtb + 1245184;            // combined (W1@W2)^T bf16, 4x
    u16* Wcgqt = wtb + 1310720;
    u16* Wcgkt = wtb + 1376256;
    u16* Wcgvt = wtb + 1441792;
    float* fb  = (float*)(wtb + 1507328);  // biases: 4x256 @0, zero @1024

    // --- prep: weight cvt + bias-combine, one launch (no input cvt)
    WtArgs wa;
    const float* wsrc[13] = {Wpq, Wgq, Wgk, Wgv, (const float*)d_in[17], (const float*)d_in[19],
                             (const float*)d_in[21], Wml,
                             (const float*)d_in[23], (const float*)d_in[25], Wl1, Wl2, Wg};
    const int wdst[13] = {0, sq, 2*sq, 3*sq, 4*sq, 5*sq, 6*sq, 7*sq, 524288, 786432,
                          1048576, 1114112, 1179648};
    for (int i = 0; i < 13; ++i){
        wa.src[i] = wsrc[i];
        wa.kdim[i] = 256; wa.ndim[i] = 256;
        wa.dstoff[i] = wdst[i];
        wa.rm[i] = (i >= 10);
    }
    wa.ndim[8] = 1024;                 // Wm1 [256][1024] -> T [1024][256]
    wa.kdim[9] = 1024;                 // Wm2 [1024][256] -> T [256][1024]
    int acc_t = 0;
    for (int i = 0; i < 13; ++i){
        wa.t0[i] = acc_t;
        acc_t += (wa.ndim[i] >> 5) * (wa.kdim[i] >> 5);
    }
    BcArgs bc;
    bc.W2[0] = Wpq; bc.W2[1] = Wgq; bc.W2[2] = Wgk; bc.W2[3] = Wgv;
    bc.b1[0] = bl1; bc.b1[1] = bg;  bc.b1[2] = bl2; bc.b1[3] = bl2;
    bc.b2[0] = bpq; bc.b2[1] = bgq; bc.b2[2] = bgk; bc.b2[3] = bgv;
    bc.off[0] = 0; bc.off[1] = 256; bc.off[2] = 512; bc.off[3] = 768;
    bc.fb = fb; bc.bc0 = acc_t;
    prep_k<<<dim3(acc_t + 4), 256, 0, stream>>>(wa, wtb, bc);

    auto GN = [&](const Grp& g, int ng, int M, int N, int K, int act, int of32){
        dim3 gr(N / 128, M / 64, ng);
        if (act)        gemm_k<1,0><<<gr, 256, 0, stream>>>(g, N, K);
        else if (of32)  gemm_k<0,1><<<gr, 256, 0, stream>>>(g, N, K);
        else            gemm_k<0,0><<<gr, 256, 0, stream>>>(g, N, K);
    };
    auto G1 = [&](const u16* A, const u16* Wt_, const float* b, void* C, int M, int N, int K,
                  float sc, int act, int of32){
        Grp g{};
        g.A[0] = A; g.Wt[0] = Wt_; g.bias[0] = b; g.C[0] = C; g.scale[0] = sc;
        GN(g, 1, M, N, K, act, of32);
    };

    // --- mini grouped GEMM: Wc^T = W2^T @ W1^T  (M=256, 32 blocks)
    {
        Grp g{};
        g.A[0] = Wpqt; g.Wt[0] = Wl1rm; g.bias[0] = fb + 1024; g.C[0] = Wcpqt; g.scale[0] = 1.f;
        g.A[1] = Wgqt; g.Wt[1] = Wgrm;  g.bias[1] = fb + 1024; g.C[1] = Wcgqt; g.scale[1] = 1.f;
        g.A[2] = Wgkt; g.Wt[2] = Wl2rm; g.bias[2] = fb + 1024; g.C[2] = Wcgkt; g.scale[2] = 1.f;
        g.A[3] = Wgvt; g.Wt[3] = Wl2rm; g.bias[3] = fb + 1024; g.C[3] = Wcgvt; g.scale[3] = 1.f;
        GN(g, 4, 256, 256, 256, 0, 0);
    }

    // --- all 6 projections in ONE grouped launch, reading fp32 inputs
    {
        Grp32 g{};
        g.A[0] = lf; g.Wt[0] = Wcpqt; g.bias[0] = fb + 0;   g.C[0] = S[3]; g.scale[0] = C1;  // pq~
        g.A[1] = gf; g.Wt[1] = Wcgqt; g.bias[1] = fb + 256; g.C[1] = S[6]; g.scale[1] = C1;  // gq~
        g.A[2] = lf; g.Wt[2] = Wcgkt; g.bias[2] = fb + 512; g.C[2] = S[7]; g.scale[2] = 1.f; // gk
        g.A[3] = lf; g.Wt[3] = Wcgvt; g.bias[3] = fb + 768; g.C[3] = S[8]; g.scale[3] = 1.f; // gv
        g.A[4] = tf; g.Wt[4] = Wpkt;  g.bias[4] = bpk;      g.C[4] = S[4]; g.scale[4] = 1.f; // pk
        g.A[5] = tf; g.Wt[5] = Wpvt;  g.bias[5] = bpv;      g.C[5] = S[5]; g.scale[5] = 1.f; // pv
        dim3 gr(2, Mn / 64, 6);
        gemm32_k<<<gr, 256, 0, stream>>>(g, 256, 256);
    }

    // --- attention: vsum = attn(pq,pk,pv) + gv ; ctx = attn(gq,gk,vsum)
    attn_k<1><<<dim3(512), 256, 0, stream>>>(S[3], S[4], S[5], S[0], S[8]);
    attn_k<0><<<dim3(512), 256, 0, stream>>>(S[6], S[7], S[0], S[1], nullptr);

    // --- output projection + MLP (unfused tail: numerics-safe)
    G1(S[1], Wdt,  bd,  S[2],  Mn, 256,  256,  1.f, 0, 0);  // out1
    G1(S[2], Wm1t, bm1, S[3],  Mn, 1024, 256,  1.f, 1, 0);  // hid = gelu(...), spans S3..S6
    G1(S[3], Wm2t, bm2, S[7],  Mn, 256,  1024, 1.f, 0, 0);  // out2
    G1(S[7], Wmlt, bml, d_out, Mn, 256,  256,  1.f, 0, 1);  // final (fp32 out)
}